// Round 1
// baseline (2381.083 us; speedup 1.0000x reference)
//
#include <hip/hip_runtime.h>
#include <math.h>

#define D_MODEL 512
#define INNER 64
#define HEADS 8
#define BATCH 4
#define SEQ 2048
#define ROWS (BATCH*SEQ)            // 8192
#define BHN (BATCH*HEADS)           // 32
#define PER_MAT ((size_t)BHN*SEQ*INNER)  // 4194304 floats = 16 MB

// ---------------------------------------------------------------------------
// Kernel 1: QKV projection.
// X (8192x512) @ Wc (512x1536) where Wc[d][n] = kernel[n>>6][d][n&63],
// scattered to Q/K/V laid out [b][h][s][k] (contiguous per (b,h)).
// 128x128 block tile, 256 threads, 8x8 per-thread register tile, BK=16.
// ---------------------------------------------------------------------------
__global__ __launch_bounds__(256) void qkv_gemm(const float* __restrict__ X,
                                                const float* __restrict__ Wk,
                                                float* __restrict__ Q,
                                                float* __restrict__ K,
                                                float* __restrict__ V) {
    __shared__ __align__(16) float As[16 * 128];   // [kk][row]
    __shared__ __align__(16) float Bs[16 * 128];   // [kk][col]
    const int t  = threadIdx.x;
    const int r0 = blockIdx.x * 128;
    const int n0 = blockIdx.y * 128;
    const int ty = t >> 4;   // 0..15 -> rows ty*8..+7
    const int tx = t & 15;   // 0..15 -> cols tx*8..+7

    float acc[8][8];
#pragma unroll
    for (int u = 0; u < 8; ++u)
#pragma unroll
        for (int v = 0; v < 8; ++v) acc[u][v] = 0.f;

    for (int k0 = 0; k0 < D_MODEL; k0 += 16) {
        __syncthreads();
        // A tile: 128 rows x 16 k, transpose-store into As[kk][row]
#pragma unroll
        for (int vv = 0; vv < 2; ++vv) {
            int v = t + vv * 256;           // 0..511 float4 ids
            int row = v >> 2, c4 = v & 3;
            float4 a = *(const float4*)&X[(size_t)(r0 + row) * D_MODEL + k0 + c4 * 4];
            As[(c4 * 4 + 0) * 128 + row] = a.x;
            As[(c4 * 4 + 1) * 128 + row] = a.y;
            As[(c4 * 4 + 2) * 128 + row] = a.z;
            As[(c4 * 4 + 3) * 128 + row] = a.w;
        }
        // B tile: 16 k x 128 n
#pragma unroll
        for (int vv = 0; vv < 2; ++vv) {
            int v = t + vv * 256;
            int dr = v >> 5, c4 = v & 31;
            int n = n0 + c4 * 4;
            float4 b = *(const float4*)&Wk[(size_t)(n >> 6) * 32768 +
                                           (size_t)(k0 + dr) * 64 + (n & 63)];
            *(float4*)&Bs[dr * 128 + c4 * 4] = b;
        }
        __syncthreads();
#pragma unroll
        for (int kk = 0; kk < 16; ++kk) {
            float4 a0 = *(const float4*)&As[kk * 128 + ty * 8];
            float4 a1 = *(const float4*)&As[kk * 128 + ty * 8 + 4];
            float4 b0 = *(const float4*)&Bs[kk * 128 + tx * 8];
            float4 b1 = *(const float4*)&Bs[kk * 128 + tx * 8 + 4];
            float ar[8] = {a0.x, a0.y, a0.z, a0.w, a1.x, a1.y, a1.z, a1.w};
            float br[8] = {b0.x, b0.y, b0.z, b0.w, b1.x, b1.y, b1.z, b1.w};
#pragma unroll
            for (int u = 0; u < 8; ++u)
#pragma unroll
                for (int v = 0; v < 8; ++v) acc[u][v] = fmaf(ar[u], br[v], acc[u][v]);
        }
    }
    // Epilogue: scatter to Q/K/V
#pragma unroll
    for (int u = 0; u < 8; ++u) {
        int r = r0 + ty * 8 + u;
        int b = r >> 11, s = r & 2047;
#pragma unroll
        for (int v4 = 0; v4 < 2; ++v4) {
            int n = n0 + tx * 8 + v4 * 4;
            int mm = n >> 6;          // 0..23
            int h = mm / 3, j = mm % 3;
            float* dst = (j == 0) ? Q : ((j == 1) ? K : V);
            float4 val = make_float4(acc[u][v4 * 4 + 0], acc[u][v4 * 4 + 1],
                                     acc[u][v4 * 4 + 2], acc[u][v4 * 4 + 3]);
            *(float4*)&dst[(((size_t)b * HEADS + h) * SEQ + s) * INNER + (n & 63)] = val;
        }
    }
}

// ---------------------------------------------------------------------------
// Kernel 2: flash attention. One wave (64 threads) per 64 query rows of one
// (b,h). Lane owns a full query row (Q, O in VGPRs). K/V tiles in LDS, read
// with wave-uniform addresses (broadcast, conflict-free). Online softmax in
// chunks of 16 keys (keeps code size within I$ and S-chunk in registers).
// ---------------------------------------------------------------------------
__global__ __launch_bounds__(64, 1) void attn(const float* __restrict__ Qg,
                                              const float* __restrict__ Kg,
                                              const float* __restrict__ Vg,
                                              float* __restrict__ Og) {
    const int lane = threadIdx.x;
    const int qt = blockIdx.x;    // 0..31 query tile
    const int bh = blockIdx.y;    // 0..31
    const size_t base = (size_t)bh * SEQ * INNER;
    const int row = qt * 64 + lane;

    __shared__ float4 Ks[1024];   // 64 keys x 16 float4
    __shared__ float4 Vs[1024];

    float4 q[16];
    const float4* qrow = (const float4*)(Qg + base + (size_t)row * INNER);
#pragma unroll
    for (int i = 0; i < 16; ++i) q[i] = qrow[i];

    float4 o[16];
#pragma unroll
    for (int i = 0; i < 16; ++i) o[i] = make_float4(0.f, 0.f, 0.f, 0.f);
    float m = -1e30f, l = 0.f;

    for (int kt = 0; kt < 32; ++kt) {
        __syncthreads();
        const float4* ksrc = (const float4*)(Kg + base + (size_t)kt * 64 * INNER);
        const float4* vsrc = (const float4*)(Vg + base + (size_t)kt * 64 * INNER);
#pragma unroll
        for (int i = 0; i < 16; ++i) {
            Ks[i * 64 + lane] = ksrc[i * 64 + lane];
            Vs[i * 64 + lane] = vsrc[i * 64 + lane];
        }
        __syncthreads();

#pragma unroll 1
        for (int cc = 0; cc < 4; ++cc) {
            float s[16];
#pragma unroll
            for (int c = 0; c < 16; ++c) {
                const float4* kr = &Ks[(cc * 16 + c) * 16];
                float acc = 0.f;
#pragma unroll
                for (int i = 0; i < 16; ++i) {
                    float4 kv = kr[i];
                    acc = fmaf(q[i].x, kv.x, acc);
                    acc = fmaf(q[i].y, kv.y, acc);
                    acc = fmaf(q[i].z, kv.z, acc);
                    acc = fmaf(q[i].w, kv.w, acc);
                }
                s[c] = acc * 0.125f;   // 1/sqrt(64)
            }
            float mt = m;
#pragma unroll
            for (int c = 0; c < 16; ++c) mt = fmaxf(mt, s[c]);
            float alpha = __expf(m - mt);
            m = mt;
            l *= alpha;
#pragma unroll
            for (int i = 0; i < 16; ++i) {
                o[i].x *= alpha; o[i].y *= alpha; o[i].z *= alpha; o[i].w *= alpha;
            }
#pragma unroll
            for (int c = 0; c < 16; ++c) {
                float p = __expf(s[c] - mt);
                l += p;
                const float4* vr = &Vs[(cc * 16 + c) * 16];
#pragma unroll
                for (int i = 0; i < 16; ++i) {
                    float4 vv = vr[i];
                    o[i].x = fmaf(p, vv.x, o[i].x);
                    o[i].y = fmaf(p, vv.y, o[i].y);
                    o[i].z = fmaf(p, vv.z, o[i].z);
                    o[i].w = fmaf(p, vv.w, o[i].w);
                }
            }
        }
    }
    float inv = 1.f / l;
    float4* orow = (float4*)(Og + base + (size_t)row * INNER);
#pragma unroll
    for (int i = 0; i < 16; ++i) {
        o[i].x *= inv; o[i].y *= inv; o[i].z *= inv; o[i].w *= inv;
        orow[i] = o[i];
    }
}

// ---------------------------------------------------------------------------
// Kernel 3: output projection. concat(O)[r][e] @ head_kernel(512x512).
// A-tile loader does the [b][h][s][k] -> [b][s][h*64+k] gather (an e-chunk
// of 16 stays inside one head, so rows are contiguous float4s).
// ---------------------------------------------------------------------------
__global__ __launch_bounds__(256) void out_proj(const float* __restrict__ O,
                                                const float* __restrict__ HK,
                                                float* __restrict__ Y) {
    __shared__ __align__(16) float As[16 * 128];
    __shared__ __align__(16) float Bs[16 * 128];
    const int t  = threadIdx.x;
    const int r0 = blockIdx.x * 128;
    const int n0 = blockIdx.y * 128;
    const int ty = t >> 4, tx = t & 15;
    const int b = r0 >> 11;   // tile fully inside one batch (2048 % 128 == 0)

    float acc[8][8];
#pragma unroll
    for (int u = 0; u < 8; ++u)
#pragma unroll
        for (int v = 0; v < 8; ++v) acc[u][v] = 0.f;

    for (int e0 = 0; e0 < D_MODEL; e0 += 16) {
        const int h = e0 >> 6, kin = e0 & 63;
        __syncthreads();
#pragma unroll
        for (int vv = 0; vv < 2; ++vv) {
            int v = t + vv * 256;
            int row = v >> 2, c4 = v & 3;
            int s = (r0 + row) & 2047;
            float4 a = *(const float4*)&O[(((size_t)b * HEADS + h) * SEQ + s) * INNER +
                                          kin + c4 * 4];
            As[(c4 * 4 + 0) * 128 + row] = a.x;
            As[(c4 * 4 + 1) * 128 + row] = a.y;
            As[(c4 * 4 + 2) * 128 + row] = a.z;
            As[(c4 * 4 + 3) * 128 + row] = a.w;
        }
#pragma unroll
        for (int vv = 0; vv < 2; ++vv) {
            int v = t + vv * 256;
            int dr = v >> 5, c4 = v & 31;
            float4 bb = *(const float4*)&HK[(size_t)(e0 + dr) * D_MODEL + n0 + c4 * 4];
            *(float4*)&Bs[dr * 128 + c4 * 4] = bb;
        }
        __syncthreads();
#pragma unroll
        for (int kk = 0; kk < 16; ++kk) {
            float4 a0 = *(const float4*)&As[kk * 128 + ty * 8];
            float4 a1 = *(const float4*)&As[kk * 128 + ty * 8 + 4];
            float4 b0 = *(const float4*)&Bs[kk * 128 + tx * 8];
            float4 b1 = *(const float4*)&Bs[kk * 128 + tx * 8 + 4];
            float ar[8] = {a0.x, a0.y, a0.z, a0.w, a1.x, a1.y, a1.z, a1.w};
            float br[8] = {b0.x, b0.y, b0.z, b0.w, b1.x, b1.y, b1.z, b1.w};
#pragma unroll
            for (int u = 0; u < 8; ++u)
#pragma unroll
                for (int v = 0; v < 8; ++v) acc[u][v] = fmaf(ar[u], br[v], acc[u][v]);
        }
    }
#pragma unroll
    for (int u = 0; u < 8; ++u) {
        int r = r0 + ty * 8 + u;
#pragma unroll
        for (int v4 = 0; v4 < 2; ++v4) {
            float4 val = make_float4(acc[u][v4 * 4 + 0], acc[u][v4 * 4 + 1],
                                     acc[u][v4 * 4 + 2], acc[u][v4 * 4 + 3]);
            *(float4*)&Y[(size_t)r * D_MODEL + n0 + tx * 8 + v4 * 4] = val;
        }
    }
}

extern "C" void kernel_launch(void* const* d_in, const int* in_sizes, int n_in,
                              void* d_out, int out_size, void* d_ws, size_t ws_size,
                              hipStream_t stream) {
    const float* x    = (const float*)d_in[0];   // (4,2048,512)
    const float* kern = (const float*)d_in[1];   // (24,512,64)
    const float* hk   = (const float*)d_in[2];   // (512,512)
    float* y = (float*)d_out;                    // (4,2048,512)
    float* ws = (float*)d_ws;
    float* Q = ws;
    float* K = ws + PER_MAT;
    float* V = ws + 2 * PER_MAT;
    float* O = ws + 3 * PER_MAT;

    qkv_gemm<<<dim3(64, 12), 256, 0, stream>>>(x, kern, Q, K, V);
    attn<<<dim3(32, 32), 64, 0, stream>>>(Q, K, V, O);
    out_proj<<<dim3(64, 4), 256, 0, stream>>>(O, hk, y);
}

// Round 2
// 581.298 us; speedup vs baseline: 4.0961x; 4.0961x over previous
//
#include <hip/hip_runtime.h>
#include <math.h>

#define D_MODEL 512
#define INNER 64
#define HEADS 8
#define BATCH 4
#define SEQ 2048
#define BHN (BATCH*HEADS)                 // 32
#define PER_MAT ((size_t)BHN*SEQ*INNER)   // 4194304 elements

typedef __attribute__((ext_vector_type(8))) short short8;   // 8 bf16 (4 VGPRs)
typedef __attribute__((ext_vector_type(4))) float floatx4;

// split fp32 -> bf16 hi (truncate) + bf16 lo (truncate of residual).
// combined representation error <= 2^-16 relative; dropped lo*lo term in
// products is <= 2^-16 relative. Well under the 1.33e-3 output threshold.
__device__ __forceinline__ void split_bf(float f, unsigned short& h, unsigned short& l) {
    unsigned int u = __float_as_uint(f);
    h = (unsigned short)(u >> 16);
    float hf = __uint_as_float(u & 0xffff0000u);
    l = (unsigned short)(__float_as_uint(f - hf) >> 16);
}

// ---------------------------------------------------------------------------
// Kernel 1: QKV projection (fp32 VALU GEMM, unchanged main loop).
// Epilogue now writes split-bf16: Qh/Ql, Kh/Kl as [bh][s][k]; V transposed
// as Vth/Vtl [bh][k][s] (so attn's PV B-fragments read contiguous runs).
// ---------------------------------------------------------------------------
__global__ __launch_bounds__(256) void qkv_gemm(const float* __restrict__ X,
                                                const float* __restrict__ Wk,
                                                unsigned short* __restrict__ Qh,
                                                unsigned short* __restrict__ Ql,
                                                unsigned short* __restrict__ Kh,
                                                unsigned short* __restrict__ Kl,
                                                unsigned short* __restrict__ Vth,
                                                unsigned short* __restrict__ Vtl) {
    __shared__ __align__(16) float As[16 * 128];   // [kk][row]
    __shared__ __align__(16) float Bs[16 * 128];   // [kk][col]
    const int t  = threadIdx.x;
    const int r0 = blockIdx.x * 128;
    const int n0 = blockIdx.y * 128;
    const int ty = t >> 4;
    const int tx = t & 15;

    float acc[8][8];
#pragma unroll
    for (int u = 0; u < 8; ++u)
#pragma unroll
        for (int v = 0; v < 8; ++v) acc[u][v] = 0.f;

    for (int k0 = 0; k0 < D_MODEL; k0 += 16) {
        __syncthreads();
#pragma unroll
        for (int vv = 0; vv < 2; ++vv) {
            int v = t + vv * 256;
            int row = v >> 2, c4 = v & 3;
            float4 a = *(const float4*)&X[(size_t)(r0 + row) * D_MODEL + k0 + c4 * 4];
            As[(c4 * 4 + 0) * 128 + row] = a.x;
            As[(c4 * 4 + 1) * 128 + row] = a.y;
            As[(c4 * 4 + 2) * 128 + row] = a.z;
            As[(c4 * 4 + 3) * 128 + row] = a.w;
        }
#pragma unroll
        for (int vv = 0; vv < 2; ++vv) {
            int v = t + vv * 256;
            int dr = v >> 5, c4 = v & 31;
            int n = n0 + c4 * 4;
            float4 b = *(const float4*)&Wk[(size_t)(n >> 6) * 32768 +
                                           (size_t)(k0 + dr) * 64 + (n & 63)];
            *(float4*)&Bs[dr * 128 + c4 * 4] = b;
        }
        __syncthreads();
#pragma unroll
        for (int kk = 0; kk < 16; ++kk) {
            float4 a0 = *(const float4*)&As[kk * 128 + ty * 8];
            float4 a1 = *(const float4*)&As[kk * 128 + ty * 8 + 4];
            float4 b0 = *(const float4*)&Bs[kk * 128 + tx * 8];
            float4 b1 = *(const float4*)&Bs[kk * 128 + tx * 8 + 4];
            float ar[8] = {a0.x, a0.y, a0.z, a0.w, a1.x, a1.y, a1.z, a1.w};
            float br[8] = {b0.x, b0.y, b0.z, b0.w, b1.x, b1.y, b1.z, b1.w};
#pragma unroll
            for (int u = 0; u < 8; ++u)
#pragma unroll
                for (int v = 0; v < 8; ++v) acc[u][v] = fmaf(ar[u], br[v], acc[u][v]);
        }
    }

    // Epilogue: split-bf16 scatter. Tile rows all in one batch (2048%128==0).
    const int b  = r0 >> 11;
    const int s0 = (r0 & 2047) + ty * 8;
#pragma unroll
    for (int v4 = 0; v4 < 2; ++v4) {
        int n = n0 + tx * 8 + v4 * 4;
        int mm = n >> 6;            // 0..23 = h*3 + j
        int h  = mm / 3, j = mm - h * 3;
        int d0 = n & 63;
        size_t bh = (size_t)b * HEADS + h;
        if (j == 2) {
            // V: transposed store, pack 8 seq values per dim -> 16B
#pragma unroll
            for (int i = 0; i < 4; ++i) {
                unsigned int hh[8], ll[8];
#pragma unroll
                for (int u = 0; u < 8; ++u) {
                    unsigned short hu, lu;
                    split_bf(acc[u][v4 * 4 + i], hu, lu);
                    hh[u] = hu; ll[u] = lu;
                }
                uint4 ph, pl;
                ph.x = hh[0] | (hh[1] << 16); ph.y = hh[2] | (hh[3] << 16);
                ph.z = hh[4] | (hh[5] << 16); ph.w = hh[6] | (hh[7] << 16);
                pl.x = ll[0] | (ll[1] << 16); pl.y = ll[2] | (ll[3] << 16);
                pl.z = ll[4] | (ll[5] << 16); pl.w = ll[6] | (ll[7] << 16);
                size_t off = (bh * INNER + d0 + i) * SEQ + s0;
                *(uint4*)&Vth[off] = ph;
                *(uint4*)&Vtl[off] = pl;
            }
        } else {
            unsigned short* dh = (j == 0) ? Qh : Kh;
            unsigned short* dl = (j == 0) ? Ql : Kl;
#pragma unroll
            for (int u = 0; u < 8; ++u) {
                unsigned int h4[4], l4[4];
#pragma unroll
                for (int i = 0; i < 4; ++i) {
                    unsigned short hu, lu;
                    split_bf(acc[u][v4 * 4 + i], hu, lu);
                    h4[i] = hu; l4[i] = lu;
                }
                uint2 ph, pl;
                ph.x = h4[0] | (h4[1] << 16); ph.y = h4[2] | (h4[3] << 16);
                pl.x = l4[0] | (l4[1] << 16); pl.y = l4[2] | (l4[3] << 16);
                size_t off = (bh * SEQ + s0 + u) * INNER + d0;
                *(uint2*)&dh[off] = ph;
                *(uint2*)&dl[off] = pl;
            }
        }
    }
}

// ---------------------------------------------------------------------------
// Kernel 2: flash attention on MFMA (16x16x32 bf16, split hi/lo 3-product).
// Block = 256 threads = 4 waves; each wave owns 16 queries; waves share a
// 64-key K/V LDS tile. Grid: blockIdx.x = bh (XCD-clusters a head's K/V in
// one L2), blockIdx.y = q-tile.
// Layouts (guide-verified): A-frag A[m=lane&15][k=quad*8+j]; C/D col=lane&15,
// row=quad*4+reg; B-frag = rows of B^T (K rows for QK^T, V^T rows for PV).
// ---------------------------------------------------------------------------
__global__ __launch_bounds__(256) void attn_mfma(
        const unsigned short* __restrict__ Qh_g, const unsigned short* __restrict__ Ql_g,
        const unsigned short* __restrict__ Kh_g, const unsigned short* __restrict__ Kl_g,
        const unsigned short* __restrict__ Vth_g, const unsigned short* __restrict__ Vtl_g,
        float* __restrict__ Og) {
    // padded stride 72 bf16 (=144B, 16B-aligned, 2-way bank aliasing = free)
    __shared__ unsigned short Ksh[64 * 72];
    __shared__ unsigned short Ksl[64 * 72];
    __shared__ unsigned short Vsh[64 * 72];   // [dim][key]
    __shared__ unsigned short Vsl[64 * 72];
    __shared__ float Pw[4][16 * 68];          // per-wave P transpose scratch

    const int t = threadIdx.x;
    const int w = t >> 6, lane = t & 63;
    const int quad = lane >> 4, l16 = lane & 15;
    const int bh = blockIdx.x;
    const int qbase = blockIdx.y * 64 + w * 16;

    // Q fragments: lane m=l16, dims chunk c: c*32 + quad*8 .. +7
    short8 qhf[2], qlf[2];
    {
        const unsigned short* p = Qh_g + ((size_t)bh * SEQ + qbase + l16) * INNER + quad * 8;
        qhf[0] = *(const short8*)p;
        qhf[1] = *(const short8*)(p + 32);
        const unsigned short* p2 = Ql_g + ((size_t)bh * SEQ + qbase + l16) * INNER + quad * 8;
        qlf[0] = *(const short8*)p2;
        qlf[1] = *(const short8*)(p2 + 32);
    }

    floatx4 o[4];
#pragma unroll
    for (int nt = 0; nt < 4; ++nt) o[nt] = (floatx4)(0.f);
    float mrun[4] = {-1e30f, -1e30f, -1e30f, -1e30f};
    float lrun[4] = {0.f, 0.f, 0.f, 0.f};

    const uint4* ksrc_h = (const uint4*)(Kh_g + (size_t)bh * SEQ * INNER);
    const uint4* ksrc_l = (const uint4*)(Kl_g + (size_t)bh * SEQ * INNER);
    const uint4* vsrc_h = (const uint4*)(Vth_g + (size_t)bh * INNER * SEQ);
    const uint4* vsrc_l = (const uint4*)(Vtl_g + (size_t)bh * INNER * SEQ);

    for (int kt = 0; kt < 32; ++kt) {
        __syncthreads();
        // stage 64-key tile: K rows [key][dim], V^T rows [dim][key]
#pragma unroll
        for (int ii = 0; ii < 2; ++ii) {
            int id = t + ii * 256;            // 0..511
            int row = id >> 3, part = id & 7; // row = key (K) or dim (V^T)
            int dst = row * 72 + part * 8;
            *(uint4*)&Ksh[dst] = ksrc_h[kt * 512 + id];
            *(uint4*)&Ksl[dst] = ksrc_l[kt * 512 + id];
            *(uint4*)&Vsh[dst] = vsrc_h[row * 256 + kt * 8 + part];
            *(uint4*)&Vsl[dst] = vsrc_l[row * 256 + kt * 8 + part];
        }
        __syncthreads();

        // ---- QK^T: 4 subtiles of 16 keys; 6 MFMAs each (2 dim-chunks x
        //      {qh*kh, qh*kl, ql*kh}) ----
        floatx4 s[4];
#pragma unroll
        for (int st = 0; st < 4; ++st) {
            const unsigned short* kph = &Ksh[(st * 16 + l16) * 72 + quad * 8];
            const unsigned short* kpl = &Ksl[(st * 16 + l16) * 72 + quad * 8];
            short8 bh0 = *(const short8*)kph;
            short8 bh1 = *(const short8*)(kph + 32);
            short8 bl0 = *(const short8*)kpl;
            short8 bl1 = *(const short8*)(kpl + 32);
            floatx4 a = (floatx4)(0.f);
            a = __builtin_amdgcn_mfma_f32_16x16x32_bf16(qhf[0], bh0, a, 0, 0, 0);
            a = __builtin_amdgcn_mfma_f32_16x16x32_bf16(qhf[1], bh1, a, 0, 0, 0);
            a = __builtin_amdgcn_mfma_f32_16x16x32_bf16(qhf[0], bl0, a, 0, 0, 0);
            a = __builtin_amdgcn_mfma_f32_16x16x32_bf16(qhf[1], bl1, a, 0, 0, 0);
            a = __builtin_amdgcn_mfma_f32_16x16x32_bf16(qlf[0], bh0, a, 0, 0, 0);
            a = __builtin_amdgcn_mfma_f32_16x16x32_bf16(qlf[1], bh1, a, 0, 0, 0);
            s[st] = a * 0.125f;               // 1/sqrt(64)
        }

        // ---- online softmax over these 64 keys ----
        floatx4 mx = s[0];
#pragma unroll
        for (int st = 1; st < 4; ++st)
#pragma unroll
            for (int r = 0; r < 4; ++r) mx[r] = fmaxf(mx[r], s[st][r]);
#pragma unroll
        for (int d = 1; d < 16; d <<= 1)
#pragma unroll
            for (int r = 0; r < 4; ++r) mx[r] = fmaxf(mx[r], __shfl_xor(mx[r], d));

        float al[4];
#pragma unroll
        for (int r = 0; r < 4; ++r) {
            float mn = fmaxf(mrun[r], mx[r]);
            al[r] = __expf(mrun[r] - mn);
            mrun[r] = mn;
        }
        floatx4 rs = (floatx4)(0.f);
#pragma unroll
        for (int st = 0; st < 4; ++st)
#pragma unroll
            for (int r = 0; r < 4; ++r) {
                float p = __expf(s[st][r] - mrun[r]);
                s[st][r] = p;
                rs[r] += p;
            }
#pragma unroll
        for (int d = 1; d < 16; d <<= 1)
#pragma unroll
            for (int r = 0; r < 4; ++r) rs[r] += __shfl_xor(rs[r], d);
#pragma unroll
        for (int r = 0; r < 4; ++r) lrun[r] = lrun[r] * al[r] + rs[r];
#pragma unroll
        for (int nt = 0; nt < 4; ++nt)
#pragma unroll
            for (int r = 0; r < 4; ++r) o[nt][r] *= al[r];

        // ---- transpose P (C/D layout -> A layout) via per-wave LDS ----
        float* pw = &Pw[w][0];
#pragma unroll
        for (int st = 0; st < 4; ++st)
#pragma unroll
            for (int r = 0; r < 4; ++r)
                pw[(quad * 4 + r) * 68 + st * 16 + l16] = s[st][r];
        asm volatile("s_waitcnt lgkmcnt(0)" ::: "memory");   // wave-internal fence

        // ---- PV: 2 key-chunks of 32; per chunk 4 n-subtiles x
        //      {ph*vh, pl*vh, ph*vl} ----
#pragma unroll
        for (int c = 0; c < 2; ++c) {
            const float* pr = pw + l16 * 68 + c * 32 + quad * 8;
            float4 pa = *(const float4*)pr;
            float4 pb = *(const float4*)(pr + 4);
            float pv[8] = {pa.x, pa.y, pa.z, pa.w, pb.x, pb.y, pb.z, pb.w};
            short8 phf, plf;
#pragma unroll
            for (int jj = 0; jj < 8; ++jj) {
                unsigned short hu, lu;
                split_bf(pv[jj], hu, lu);
                phf[jj] = (short)hu;
                plf[jj] = (short)lu;
            }
#pragma unroll
            for (int nt = 0; nt < 4; ++nt) {
                const unsigned short* vph = &Vsh[(nt * 16 + l16) * 72 + c * 32 + quad * 8];
                const unsigned short* vpl = &Vsl[(nt * 16 + l16) * 72 + c * 32 + quad * 8];
                short8 vh = *(const short8*)vph;
                short8 vl = *(const short8*)vpl;
                o[nt] = __builtin_amdgcn_mfma_f32_16x16x32_bf16(phf, vh, o[nt], 0, 0, 0);
                o[nt] = __builtin_amdgcn_mfma_f32_16x16x32_bf16(plf, vh, o[nt], 0, 0, 0);
                o[nt] = __builtin_amdgcn_mfma_f32_16x16x32_bf16(phf, vl, o[nt], 0, 0, 0);
            }
        }
    }

    // normalize + write O [bh][q][dim] fp32
#pragma unroll
    for (int r = 0; r < 4; ++r) {
        float inv = 1.f / lrun[r];
        size_t row = (size_t)bh * SEQ + qbase + quad * 4 + r;
#pragma unroll
        for (int nt = 0; nt < 4; ++nt)
            Og[row * INNER + nt * 16 + l16] = o[nt][r] * inv;
    }
}

// ---------------------------------------------------------------------------
// Kernel 3: output projection (unchanged, reads fp32 O).
// ---------------------------------------------------------------------------
__global__ __launch_bounds__(256) void out_proj(const float* __restrict__ O,
                                                const float* __restrict__ HK,
                                                float* __restrict__ Y) {
    __shared__ __align__(16) float As[16 * 128];
    __shared__ __align__(16) float Bs[16 * 128];
    const int t  = threadIdx.x;
    const int r0 = blockIdx.x * 128;
    const int n0 = blockIdx.y * 128;
    const int ty = t >> 4, tx = t & 15;
    const int b = r0 >> 11;

    float acc[8][8];
#pragma unroll
    for (int u = 0; u < 8; ++u)
#pragma unroll
        for (int v = 0; v < 8; ++v) acc[u][v] = 0.f;

    for (int e0 = 0; e0 < D_MODEL; e0 += 16) {
        const int h = e0 >> 6, kin = e0 & 63;
        __syncthreads();
#pragma unroll
        for (int vv = 0; vv < 2; ++vv) {
            int v = t + vv * 256;
            int row = v >> 2, c4 = v & 3;
            int s = (r0 + row) & 2047;
            float4 a = *(const float4*)&O[(((size_t)b * HEADS + h) * SEQ + s) * INNER +
                                          kin + c4 * 4];
            As[(c4 * 4 + 0) * 128 + row] = a.x;
            As[(c4 * 4 + 1) * 128 + row] = a.y;
            As[(c4 * 4 + 2) * 128 + row] = a.z;
            As[(c4 * 4 + 3) * 128 + row] = a.w;
        }
#pragma unroll
        for (int vv = 0; vv < 2; ++vv) {
            int v = t + vv * 256;
            int dr = v >> 5, c4 = v & 31;
            float4 bb = *(const float4*)&HK[(size_t)(e0 + dr) * D_MODEL + n0 + c4 * 4];
            *(float4*)&Bs[dr * 128 + c4 * 4] = bb;
        }
        __syncthreads();
#pragma unroll
        for (int kk = 0; kk < 16; ++kk) {
            float4 a0 = *(const float4*)&As[kk * 128 + ty * 8];
            float4 a1 = *(const float4*)&As[kk * 128 + ty * 8 + 4];
            float4 b0 = *(const float4*)&Bs[kk * 128 + tx * 8];
            float4 b1 = *(const float4*)&Bs[kk * 128 + tx * 8 + 4];
            float ar[8] = {a0.x, a0.y, a0.z, a0.w, a1.x, a1.y, a1.z, a1.w};
            float br[8] = {b0.x, b0.y, b0.z, b0.w, b1.x, b1.y, b1.z, b1.w};
#pragma unroll
            for (int u = 0; u < 8; ++u)
#pragma unroll
                for (int v = 0; v < 8; ++v) acc[u][v] = fmaf(ar[u], br[v], acc[u][v]);
        }
    }
#pragma unroll
    for (int u = 0; u < 8; ++u) {
        int r = r0 + ty * 8 + u;
#pragma unroll
        for (int v4 = 0; v4 < 2; ++v4) {
            float4 val = make_float4(acc[u][v4 * 4 + 0], acc[u][v4 * 4 + 1],
                                     acc[u][v4 * 4 + 2], acc[u][v4 * 4 + 3]);
            *(float4*)&Y[(size_t)r * D_MODEL + n0 + tx * 8 + v4 * 4] = val;
        }
    }
}

extern "C" void kernel_launch(void* const* d_in, const int* in_sizes, int n_in,
                              void* d_out, int out_size, void* d_ws, size_t ws_size,
                              hipStream_t stream) {
    const float* x    = (const float*)d_in[0];
    const float* kern = (const float*)d_in[1];
    const float* hk   = (const float*)d_in[2];
    float* y = (float*)d_out;

    unsigned short* Qh  = (unsigned short*)d_ws;
    unsigned short* Ql  = Qh + PER_MAT;
    unsigned short* Kh  = Qh + 2 * PER_MAT;
    unsigned short* Kl  = Qh + 3 * PER_MAT;
    unsigned short* Vth = Qh + 4 * PER_MAT;
    unsigned short* Vtl = Qh + 5 * PER_MAT;
    float* O = (float*)((char*)d_ws + 6 * PER_MAT * sizeof(unsigned short));

    qkv_gemm<<<dim3(64, 12), 256, 0, stream>>>(x, kern, Qh, Ql, Kh, Kl, Vth, Vtl);
    attn_mfma<<<dim3(32, 32), 256, 0, stream>>>(Qh, Ql, Kh, Kl, Vth, Vtl, O);
    out_proj<<<dim3(64, 4), 256, 0, stream>>>(O, hk, y);
}

// Round 4
// 486.660 us; speedup vs baseline: 4.8927x; 1.1945x over previous
//
#include <hip/hip_runtime.h>
#include <math.h>

#define D_MODEL 512
#define INNER 64
#define HEADS 8
#define BATCH 4
#define SEQ 2048
#define BHN (BATCH*HEADS)                 // 32
#define PER_MAT ((size_t)BHN*SEQ*INNER)   // 4194304 elements

typedef __attribute__((ext_vector_type(8))) short short8;   // 8 bf16 (4 VGPRs)
typedef __attribute__((ext_vector_type(4))) float floatx4;

// split fp32 -> bf16 hi (truncate) + bf16 lo (truncate of residual).
__device__ __forceinline__ void split_bf(float f, unsigned short& h, unsigned short& l) {
    unsigned int u = __float_as_uint(f);
    h = (unsigned short)(u >> 16);
    float hf = __uint_as_float(u & 0xffff0000u);
    l = (unsigned short)(__float_as_uint(f - hf) >> 16);
}

// ---------------------------------------------------------------------------
// Kernel 1: QKV projection (fp32 VALU GEMM). Q pre-scaled by 1/sqrt(64).
// Outputs: Qh/Ql, Kh/Kl [bh][s][k]; Vth/Vtl transposed [bh][k][s].
// ---------------------------------------------------------------------------
__global__ __launch_bounds__(256) void qkv_gemm(const float* __restrict__ X,
                                                const float* __restrict__ Wk,
                                                unsigned short* __restrict__ Qh,
                                                unsigned short* __restrict__ Ql,
                                                unsigned short* __restrict__ Kh,
                                                unsigned short* __restrict__ Kl,
                                                unsigned short* __restrict__ Vth,
                                                unsigned short* __restrict__ Vtl) {
    __shared__ __align__(16) float As[16 * 128];   // [kk][row]
    __shared__ __align__(16) float Bs[16 * 128];   // [kk][col]
    const int t  = threadIdx.x;
    const int r0 = blockIdx.x * 128;
    const int n0 = blockIdx.y * 128;
    const int ty = t >> 4;
    const int tx = t & 15;

    float acc[8][8];
#pragma unroll
    for (int u = 0; u < 8; ++u)
#pragma unroll
        for (int v = 0; v < 8; ++v) acc[u][v] = 0.f;

    for (int k0 = 0; k0 < D_MODEL; k0 += 16) {
        __syncthreads();
#pragma unroll
        for (int vv = 0; vv < 2; ++vv) {
            int v = t + vv * 256;
            int row = v >> 2, c4 = v & 3;
            float4 a = *(const float4*)&X[(size_t)(r0 + row) * D_MODEL + k0 + c4 * 4];
            As[(c4 * 4 + 0) * 128 + row] = a.x;
            As[(c4 * 4 + 1) * 128 + row] = a.y;
            As[(c4 * 4 + 2) * 128 + row] = a.z;
            As[(c4 * 4 + 3) * 128 + row] = a.w;
        }
#pragma unroll
        for (int vv = 0; vv < 2; ++vv) {
            int v = t + vv * 256;
            int dr = v >> 5, c4 = v & 31;
            int n = n0 + c4 * 4;
            float4 b = *(const float4*)&Wk[(size_t)(n >> 6) * 32768 +
                                           (size_t)(k0 + dr) * 64 + (n & 63)];
            *(float4*)&Bs[dr * 128 + c4 * 4] = b;
        }
        __syncthreads();
#pragma unroll
        for (int kk = 0; kk < 16; ++kk) {
            float4 a0 = *(const float4*)&As[kk * 128 + ty * 8];
            float4 a1 = *(const float4*)&As[kk * 128 + ty * 8 + 4];
            float4 b0 = *(const float4*)&Bs[kk * 128 + tx * 8];
            float4 b1 = *(const float4*)&Bs[kk * 128 + tx * 8 + 4];
            float ar[8] = {a0.x, a0.y, a0.z, a0.w, a1.x, a1.y, a1.z, a1.w};
            float br[8] = {b0.x, b0.y, b0.z, b0.w, b1.x, b1.y, b1.z, b1.w};
#pragma unroll
            for (int u = 0; u < 8; ++u)
#pragma unroll
                for (int v = 0; v < 8; ++v) acc[u][v] = fmaf(ar[u], br[v], acc[u][v]);
        }
    }

    const int b  = r0 >> 11;
    const int s0 = (r0 & 2047) + ty * 8;
#pragma unroll
    for (int v4 = 0; v4 < 2; ++v4) {
        int n = n0 + tx * 8 + v4 * 4;
        int mm = n >> 6;            // 0..23 = h*3 + j
        int h  = mm / 3, j = mm - h * 3;
        int d0 = n & 63;
        size_t bh = (size_t)b * HEADS + h;
        if (j == 2) {
            // V: transposed store
#pragma unroll
            for (int i = 0; i < 4; ++i) {
                unsigned int hh[8], ll[8];
#pragma unroll
                for (int u = 0; u < 8; ++u) {
                    unsigned short hu, lu;
                    split_bf(acc[u][v4 * 4 + i], hu, lu);
                    hh[u] = hu; ll[u] = lu;
                }
                uint4 ph, pl;
                ph.x = hh[0] | (hh[1] << 16); ph.y = hh[2] | (hh[3] << 16);
                ph.z = hh[4] | (hh[5] << 16); ph.w = hh[6] | (hh[7] << 16);
                pl.x = ll[0] | (ll[1] << 16); pl.y = ll[2] | (ll[3] << 16);
                pl.z = ll[4] | (ll[5] << 16); pl.w = ll[6] | (ll[7] << 16);
                size_t off = (bh * INNER + d0 + i) * SEQ + s0;
                *(uint4*)&Vth[off] = ph;
                *(uint4*)&Vtl[off] = pl;
            }
        } else {
            unsigned short* dh = (j == 0) ? Qh : Kh;
            unsigned short* dl = (j == 0) ? Ql : Kl;
            const float scale = (j == 0) ? 0.125f : 1.0f;   // fold 1/sqrt(64) into Q
#pragma unroll
            for (int u = 0; u < 8; ++u) {
                unsigned int h4[4], l4[4];
#pragma unroll
                for (int i = 0; i < 4; ++i) {
                    unsigned short hu, lu;
                    split_bf(acc[u][v4 * 4 + i] * scale, hu, lu);
                    h4[i] = hu; l4[i] = lu;
                }
                uint2 ph, pl;
                ph.x = h4[0] | (h4[1] << 16); ph.y = h4[2] | (h4[3] << 16);
                pl.x = l4[0] | (l4[1] << 16); pl.y = l4[2] | (l4[3] << 16);
                size_t off = (bh * SEQ + s0 + u) * INNER + d0;
                *(uint2*)&dh[off] = ph;
                *(uint2*)&dl[off] = pl;
            }
        }
    }
}

// ---------------------------------------------------------------------------
// Kernel 2: flash attention, S^T/O^T orientation.
//   S^T = MFMA(A=K, B=Q)  -> lane holds query=l16 (softmax state per-lane)
//   O^T = MFMA(A=V^T,B=P) -> lane holds query=l16, dims quad*4+r per subtile
// Wave = 32 queries; block = 4 waves = 128 queries.
// P scratch aliases the K LDS buffers, HALF (32 keys) at a time:
//   per wave 32 rows x 36 floats = 4608 B; 4 waves = 18432 B = sizeof(Kboth).
// LDS = 36.9 KB -> 4 blocks/CU.
// ---------------------------------------------------------------------------
__global__ __launch_bounds__(256, 4) void attn_mfma(
        const unsigned short* __restrict__ Qh_g, const unsigned short* __restrict__ Ql_g,
        const unsigned short* __restrict__ Kh_g, const unsigned short* __restrict__ Kl_g,
        const unsigned short* __restrict__ Vth_g, const unsigned short* __restrict__ Vtl_g,
        float* __restrict__ Og) {
    // stride 72 shorts = 144 B (16B-aligned rows, bank-floor patterns)
    __shared__ unsigned short Kboth[2][64 * 72];   // [hi/lo][key][dim]; P scratch aliases
    __shared__ unsigned short Vsh[64 * 72];        // [dim][key]
    __shared__ unsigned short Vsl[64 * 72];

    const int t = threadIdx.x;
    const int w = t >> 6, lane = t & 63;
    const int quad = lane >> 4, l16 = lane & 15;
    const int bh = blockIdx.x;
    const int qbase = blockIdx.y * 128 + w * 32;

    unsigned short* Ksh = &Kboth[0][0];
    unsigned short* Ksl = &Kboth[1][0];
    // per-wave P scratch: 32 queries x 36-float stride (144 B rows) = 4608 B
    float* pw = (float*)&Kboth[0][0] + w * 1152;

    // Q fragments (pre-scaled): lane n=l16 -> query, k=quad*8+j -> dim
    short8 qhf[2][2], qlf[2][2];
#pragma unroll
    for (int qg = 0; qg < 2; ++qg) {
        const unsigned short* p = Qh_g + ((size_t)bh * SEQ + qbase + qg * 16 + l16) * INNER + quad * 8;
        qhf[qg][0] = *(const short8*)p;
        qhf[qg][1] = *(const short8*)(p + 32);
        const unsigned short* p2 = Ql_g + ((size_t)bh * SEQ + qbase + qg * 16 + l16) * INNER + quad * 8;
        qlf[qg][0] = *(const short8*)p2;
        qlf[qg][1] = *(const short8*)(p2 + 32);
    }

    floatx4 o[2][4];
#pragma unroll
    for (int qg = 0; qg < 2; ++qg)
#pragma unroll
        for (int nt = 0; nt < 4; ++nt) o[qg][nt] = (floatx4)(0.f);
    float mrun[2] = {-1e30f, -1e30f};
    float lrun[2] = {0.f, 0.f};

    const uint4* ksrc_h = (const uint4*)(Kh_g + (size_t)bh * SEQ * INNER);
    const uint4* ksrc_l = (const uint4*)(Kl_g + (size_t)bh * SEQ * INNER);
    const uint4* vsrc_h = (const uint4*)(Vth_g + (size_t)bh * INNER * SEQ);
    const uint4* vsrc_l = (const uint4*)(Vtl_g + (size_t)bh * INNER * SEQ);

    for (int kt = 0; kt < 32; ++kt) {
        __syncthreads();   // (A) prior PV + P reads done -> safe to restage K/V
#pragma unroll
        for (int ii = 0; ii < 2; ++ii) {
            int id = t + ii * 256;            // 0..511
            int row = id >> 3, part = id & 7; // row = key (K) or dim (V^T)
            int dst = row * 72 + part * 8;
            *(uint4*)&Ksh[dst] = ksrc_h[kt * 512 + id];
            *(uint4*)&Ksl[dst] = ksrc_l[kt * 512 + id];
            *(uint4*)&Vsh[dst] = vsrc_h[row * 256 + kt * 8 + part];
            *(uint4*)&Vsl[dst] = vsrc_l[row * 256 + kt * 8 + part];
        }
        __syncthreads();   // (B) staging visible

        // ---- S^T: 4 subtiles of 16 keys; A=K frags shared across qgroups ----
        floatx4 s[2][4];
#pragma unroll
        for (int st = 0; st < 4; ++st) {
            const unsigned short* ka = &Ksh[(st * 16 + l16) * 72 + quad * 8];
            const unsigned short* kb = &Ksl[(st * 16 + l16) * 72 + quad * 8];
            short8 kh0 = *(const short8*)ka;
            short8 kh1 = *(const short8*)(ka + 32);
            short8 kl0 = *(const short8*)kb;
            short8 kl1 = *(const short8*)(kb + 32);
#pragma unroll
            for (int qg = 0; qg < 2; ++qg) {
                floatx4 a = (floatx4)(0.f);
                a = __builtin_amdgcn_mfma_f32_16x16x32_bf16(kh0, qhf[qg][0], a, 0, 0, 0);
                a = __builtin_amdgcn_mfma_f32_16x16x32_bf16(kh1, qhf[qg][1], a, 0, 0, 0);
                a = __builtin_amdgcn_mfma_f32_16x16x32_bf16(kl0, qhf[qg][0], a, 0, 0, 0);
                a = __builtin_amdgcn_mfma_f32_16x16x32_bf16(kl1, qhf[qg][1], a, 0, 0, 0);
                a = __builtin_amdgcn_mfma_f32_16x16x32_bf16(kh0, qlf[qg][0], a, 0, 0, 0);
                a = __builtin_amdgcn_mfma_f32_16x16x32_bf16(kh1, qlf[qg][1], a, 0, 0, 0);
                s[qg][st] = a;
            }
        }

        // ---- online softmax: per-lane query, in-lane over 16 keys + 2 shfl ----
#pragma unroll
        for (int qg = 0; qg < 2; ++qg) {
            float mloc = s[qg][0][0];
#pragma unroll
            for (int st = 0; st < 4; ++st)
#pragma unroll
                for (int r = 0; r < 4; ++r) mloc = fmaxf(mloc, s[qg][st][r]);
            mloc = fmaxf(mloc, __shfl_xor(mloc, 16));
            mloc = fmaxf(mloc, __shfl_xor(mloc, 32));
            float mn = fmaxf(mrun[qg], mloc);
            float alpha = __expf(mrun[qg] - mn);
            mrun[qg] = mn;
            float rs = 0.f;
#pragma unroll
            for (int st = 0; st < 4; ++st)
#pragma unroll
                for (int r = 0; r < 4; ++r) {
                    float p = __expf(s[qg][st][r] - mn);
                    s[qg][st][r] = p;
                    rs += p;
                }
            rs += __shfl_xor(rs, 16);
            rs += __shfl_xor(rs, 32);
            lrun[qg] = lrun[qg] * alpha + rs;
#pragma unroll
            for (int nt = 0; nt < 4; ++nt) o[qg][nt] = o[qg][nt] * alpha;
        }

        __syncthreads();   // (C) all waves done reading K -> safe to scribble P

        // ---- PV in two halves of 32 keys; P transpose through per-wave LDS ----
#pragma unroll
        for (int half = 0; half < 2; ++half) {
            asm volatile("" ::: "memory");   // pin order vs previous half's reads
            // write P rows (C/D key-rows -> query-row scratch), keys half*32..+31
#pragma unroll
            for (int qg = 0; qg < 2; ++qg)
#pragma unroll
                for (int st2 = 0; st2 < 2; ++st2) {
                    int st = half * 2 + st2;
                    float4 v = make_float4(s[qg][st][0], s[qg][st][1],
                                           s[qg][st][2], s[qg][st][3]);
                    *(float4*)&pw[(qg * 16 + l16) * 36 + st2 * 16 + quad * 4] = v;
                }
            asm volatile("s_waitcnt lgkmcnt(0)" ::: "memory");   // wave-internal

            short8 phf[2], plf[2];
#pragma unroll
            for (int qg = 0; qg < 2; ++qg) {
                const float* pr = &pw[(qg * 16 + l16) * 36 + quad * 8];
                float4 pa = *(const float4*)pr;
                float4 pb = *(const float4*)(pr + 4);
                float pv[8] = {pa.x, pa.y, pa.z, pa.w, pb.x, pb.y, pb.z, pb.w};
#pragma unroll
                for (int jj = 0; jj < 8; ++jj) {
                    unsigned short hu, lu;
                    split_bf(pv[jj], hu, lu);
                    phf[qg][jj] = (short)hu;
                    plf[qg][jj] = (short)lu;
                }
            }
#pragma unroll
            for (int nt = 0; nt < 4; ++nt) {
                const unsigned short* va = &Vsh[(nt * 16 + l16) * 72 + half * 32 + quad * 8];
                const unsigned short* vb = &Vsl[(nt * 16 + l16) * 72 + half * 32 + quad * 8];
                short8 vh = *(const short8*)va;
                short8 vl = *(const short8*)vb;
#pragma unroll
                for (int qg = 0; qg < 2; ++qg) {
                    o[qg][nt] = __builtin_amdgcn_mfma_f32_16x16x32_bf16(vh, phf[qg], o[qg][nt], 0, 0, 0);
                    o[qg][nt] = __builtin_amdgcn_mfma_f32_16x16x32_bf16(vh, plf[qg], o[qg][nt], 0, 0, 0);
                    o[qg][nt] = __builtin_amdgcn_mfma_f32_16x16x32_bf16(vl, phf[qg], o[qg][nt], 0, 0, 0);
                }
            }
        }
    }

    // epilogue: lane holds query qg*16+l16, dims nt*16+quad*4+r
#pragma unroll
    for (int qg = 0; qg < 2; ++qg) {
        float inv = 1.f / lrun[qg];
        size_t row = (size_t)bh * SEQ + qbase + qg * 16 + l16;
#pragma unroll
        for (int nt = 0; nt < 4; ++nt) {
            float4 v = make_float4(o[qg][nt][0] * inv, o[qg][nt][1] * inv,
                                   o[qg][nt][2] * inv, o[qg][nt][3] * inv);
            *(float4*)&Og[row * INNER + nt * 16 + quad * 4] = v;
        }
    }
}

// ---------------------------------------------------------------------------
// Kernel 3: output projection (unchanged).
// ---------------------------------------------------------------------------
__global__ __launch_bounds__(256) void out_proj(const float* __restrict__ O,
                                                const float* __restrict__ HK,
                                                float* __restrict__ Y) {
    __shared__ __align__(16) float As[16 * 128];
    __shared__ __align__(16) float Bs[16 * 128];
    const int t  = threadIdx.x;
    const int r0 = blockIdx.x * 128;
    const int n0 = blockIdx.y * 128;
    const int ty = t >> 4, tx = t & 15;
    const int b = r0 >> 11;

    float acc[8][8];
#pragma unroll
    for (int u = 0; u < 8; ++u)
#pragma unroll
        for (int v = 0; v < 8; ++v) acc[u][v] = 0.f;

    for (int e0 = 0; e0 < D_MODEL; e0 += 16) {
        const int h = e0 >> 6, kin = e0 & 63;
        __syncthreads();
#pragma unroll
        for (int vv = 0; vv < 2; ++vv) {
            int v = t + vv * 256;
            int row = v >> 2, c4 = v & 3;
            int s = (r0 + row) & 2047;
            float4 a = *(const float4*)&O[(((size_t)b * HEADS + h) * SEQ + s) * INNER +
                                          kin + c4 * 4];
            As[(c4 * 4 + 0) * 128 + row] = a.x;
            As[(c4 * 4 + 1) * 128 + row] = a.y;
            As[(c4 * 4 + 2) * 128 + row] = a.z;
            As[(c4 * 4 + 3) * 128 + row] = a.w;
        }
#pragma unroll
        for (int vv = 0; vv < 2; ++vv) {
            int v = t + vv * 256;
            int dr = v >> 5, c4 = v & 31;
            float4 bb = *(const float4*)&HK[(size_t)(e0 + dr) * D_MODEL + n0 + c4 * 4];
            *(float4*)&Bs[dr * 128 + c4 * 4] = bb;
        }
        __syncthreads();
#pragma unroll
        for (int kk = 0; kk < 16; ++kk) {
            float4 a0 = *(const float4*)&As[kk * 128 + ty * 8];
            float4 a1 = *(const float4*)&As[kk * 128 + ty * 8 + 4];
            float4 b0 = *(const float4*)&Bs[kk * 128 + tx * 8];
            float4 b1 = *(const float4*)&Bs[kk * 128 + tx * 8 + 4];
            float ar[8] = {a0.x, a0.y, a0.z, a0.w, a1.x, a1.y, a1.z, a1.w};
            float br[8] = {b0.x, b0.y, b0.z, b0.w, b1.x, b1.y, b1.z, b1.w};
#pragma unroll
            for (int u = 0; u < 8; ++u)
#pragma unroll
                for (int v = 0; v < 8; ++v) acc[u][v] = fmaf(ar[u], br[v], acc[u][v]);
        }
    }
#pragma unroll
    for (int u = 0; u < 8; ++u) {
        int r = r0 + ty * 8 + u;
#pragma unroll
        for (int v4 = 0; v4 < 2; ++v4) {
            float4 val = make_float4(acc[u][v4 * 4 + 0], acc[u][v4 * 4 + 1],
                                     acc[u][v4 * 4 + 2], acc[u][v4 * 4 + 3]);
            *(float4*)&Y[(size_t)r * D_MODEL + n0 + tx * 8 + v4 * 4] = val;
        }
    }
}

extern "C" void kernel_launch(void* const* d_in, const int* in_sizes, int n_in,
                              void* d_out, int out_size, void* d_ws, size_t ws_size,
                              hipStream_t stream) {
    const float* x    = (const float*)d_in[0];
    const float* kern = (const float*)d_in[1];
    const float* hk   = (const float*)d_in[2];
    float* y = (float*)d_out;

    unsigned short* Qh  = (unsigned short*)d_ws;
    unsigned short* Ql  = Qh + PER_MAT;
    unsigned short* Kh  = Qh + 2 * PER_MAT;
    unsigned short* Kl  = Qh + 3 * PER_MAT;
    unsigned short* Vth = Qh + 4 * PER_MAT;
    unsigned short* Vtl = Qh + 5 * PER_MAT;
    float* O = (float*)((char*)d_ws + 6 * PER_MAT * sizeof(unsigned short));

    qkv_gemm<<<dim3(64, 12), 256, 0, stream>>>(x, kern, Qh, Ql, Kh, Kl, Vth, Vtl);
    attn_mfma<<<dim3(32, 16), 256, 0, stream>>>(Qh, Ql, Kh, Kl, Vth, Vtl, O);
    out_proj<<<dim3(64, 4), 256, 0, stream>>>(O, hk, y);
}

// Round 6
// 435.735 us; speedup vs baseline: 5.4645x; 1.1169x over previous
//
#include <hip/hip_runtime.h>
#include <math.h>

#define D_MODEL 512
#define INNER 64
#define HEADS 8
#define BATCH 4
#define SEQ 2048
#define BHN (BATCH*HEADS)                 // 32
#define PER_MAT ((size_t)BHN*SEQ*INNER)   // 4194304 elements

typedef __attribute__((ext_vector_type(8))) short short8;   // 8 bf16 (4 VGPRs)
typedef __attribute__((ext_vector_type(4))) float floatx4;

// split fp32 -> bf16 hi (truncate) + bf16 lo (truncate of residual)
__device__ __forceinline__ void split_bf(float f, unsigned short& h, unsigned short& l) {
    unsigned int u = __float_as_uint(f);
    h = (unsigned short)(u >> 16);
    float hf = __uint_as_float(u & 0xffff0000u);
    l = (unsigned short)(__float_as_uint(f - hf) >> 16);
}

__device__ __forceinline__ void split4(const float* f, uint2& ph, uint2& pl) {
    unsigned int h[4], l[4];
#pragma unroll
    for (int j = 0; j < 4; ++j) {
        unsigned short hu, lu;
        split_bf(f[j], hu, lu);
        h[j] = hu; l[j] = lu;
    }
    ph.x = h[0] | (h[1] << 16); ph.y = h[2] | (h[3] << 16);
    pl.x = l[0] | (l[1] << 16); pl.y = l[2] | (l[3] << 16);
}

// ---------------------------------------------------------------------------
// Prep 1: W (24 mats of 512x64 fp32) -> Wt hi/lo bf16 [n=1536][k=512],
// Wt[n][k] = kernel[n>>6][k][n&63]. LDS-tiled 64x64 transpose.
// Write phase: 64 rows x 4 k-chunks = 256 work items = ONE pass (R5 bug: 4).
// ---------------------------------------------------------------------------
__global__ __launch_bounds__(256) void split_w(const float* __restrict__ kern,
                                               unsigned short* __restrict__ Wth,
                                               unsigned short* __restrict__ Wtl) {
    __shared__ float tile[64 * 65];
    const int t = threadIdx.x;
    const int mat = blockIdx.x, k0 = blockIdx.y * 64;
#pragma unroll
    for (int c = 0; c < 4; ++c) {
        int idx = t + c * 256;          // 0..1023 float4 ids (64 k x 16 i4)
        int kl = idx >> 4, i4 = idx & 15;
        float4 v = *(const float4*)&kern[((size_t)mat * 512 + k0 + kl) * 64 + i4 * 4];
        tile[(i4 * 4 + 0) * 65 + kl] = v.x;
        tile[(i4 * 4 + 1) * 65 + kl] = v.y;
        tile[(i4 * 4 + 2) * 65 + kl] = v.z;
        tile[(i4 * 4 + 3) * 65 + kl] = v.w;
    }
    __syncthreads();
    {
        int idx = t;                    // 0..255: i = 0..63, kq = 0..3
        int i = idx >> 2, kq = idx & 3;
        uint2 h0, l0, h1, l1, h2, l2, h3, l3;
        float f[16];
#pragma unroll
        for (int jj = 0; jj < 16; ++jj) f[jj] = tile[i * 65 + kq * 16 + jj];
        split4(f, h0, l0); split4(f + 4, h1, l1);
        split4(f + 8, h2, l2); split4(f + 12, h3, l3);
        size_t off = ((size_t)mat * 64 + i) * 512 + k0 + kq * 16;
        *(uint4*)&Wth[off]     = make_uint4(h0.x, h0.y, h1.x, h1.y);
        *(uint4*)&Wth[off + 8] = make_uint4(h2.x, h2.y, h3.x, h3.y);
        *(uint4*)&Wtl[off]     = make_uint4(l0.x, l0.y, l1.x, l1.y);
        *(uint4*)&Wtl[off + 8] = make_uint4(l2.x, l2.y, l3.x, l3.y);
    }
}

// ---------------------------------------------------------------------------
// Prep 2: HK (512x512 fp32) -> HKt hi/lo bf16 [n=512][k=512] (transpose).
// Write phase: single 256-item pass (R5 bug fixed).
// ---------------------------------------------------------------------------
__global__ __launch_bounds__(256) void split_hk(const float* __restrict__ HK,
                                                unsigned short* __restrict__ Hth,
                                                unsigned short* __restrict__ Htl) {
    __shared__ float tile[64 * 65];
    const int t = threadIdx.x;
    const int n0 = blockIdx.x * 64, k0 = blockIdx.y * 64;
#pragma unroll
    for (int c = 0; c < 4; ++c) {
        int idx = t + c * 256;
        int kl = idx >> 4, n4 = idx & 15;
        float4 v = *(const float4*)&HK[(size_t)(k0 + kl) * 512 + n0 + n4 * 4];
        tile[(n4 * 4 + 0) * 65 + kl] = v.x;
        tile[(n4 * 4 + 1) * 65 + kl] = v.y;
        tile[(n4 * 4 + 2) * 65 + kl] = v.z;
        tile[(n4 * 4 + 3) * 65 + kl] = v.w;
    }
    __syncthreads();
    {
        int idx = t;                    // 0..255: i = 0..63, kq = 0..3
        int i = idx >> 2, kq = idx & 3;
        uint2 h0, l0, h1, l1, h2, l2, h3, l3;
        float f[16];
#pragma unroll
        for (int jj = 0; jj < 16; ++jj) f[jj] = tile[i * 65 + kq * 16 + jj];
        split4(f, h0, l0); split4(f + 4, h1, l1);
        split4(f + 8, h2, l2); split4(f + 12, h3, l3);
        size_t off = (size_t)(n0 + i) * 512 + k0 + kq * 16;
        *(uint4*)&Hth[off]     = make_uint4(h0.x, h0.y, h1.x, h1.y);
        *(uint4*)&Hth[off + 8] = make_uint4(h2.x, h2.y, h3.x, h3.y);
        *(uint4*)&Htl[off]     = make_uint4(l0.x, l0.y, l1.x, l1.y);
        *(uint4*)&Htl[off + 8] = make_uint4(l2.x, l2.y, l3.x, l3.y);
    }
}

// ---------------------------------------------------------------------------
// Kernel 1: QKV projection, split-bf16 MFMA (3-term hi/lo).
// C = X(8192x512) @ W(512x1536). 128x128 tile, BK=32, 4 waves of 64x64.
// Wave n-span = exactly one Q/K/V sub-matrix -> wave-uniform epilogue:
// acc -> padded LDS repack -> coalesced uint4 split stores (V transposed).
// ---------------------------------------------------------------------------
__global__ __launch_bounds__(256) void qkv_mfma(const float* __restrict__ X,
                                                const unsigned short* __restrict__ Wth,
                                                const unsigned short* __restrict__ Wtl,
                                                unsigned short* __restrict__ Qh,
                                                unsigned short* __restrict__ Ql,
                                                unsigned short* __restrict__ Kh,
                                                unsigned short* __restrict__ Kl,
                                                unsigned short* __restrict__ Vth,
                                                unsigned short* __restrict__ Vtl) {
    __shared__ __align__(16) unsigned short smem[16384];   // 32 KB
    unsigned short* Ah = smem;            // [m][k] 128x32
    unsigned short* Al = smem + 4096;
    unsigned short* Bh = smem + 8192;     // [n][k] 128x32
    unsigned short* Bl = smem + 12288;

    const int t = threadIdx.x;
    const int w = t >> 6, lane = t & 63;
    const int quad = lane >> 4, l16 = lane & 15;
    const int wm = w & 1, wn = w >> 1;
    const int r0 = blockIdx.x * 128, n0 = blockIdx.y * 128;

    floatx4 acc[4][4];
#pragma unroll
    for (int mt = 0; mt < 4; ++mt)
#pragma unroll
        for (int nt = 0; nt < 4; ++nt) acc[mt][nt] = (floatx4)(0.f);

    for (int ko = 0; ko < 16; ++ko) {
        const int k0 = ko * 32;
        __syncthreads();
        // A stage: X fp32 -> split bf16 LDS
#pragma unroll
        for (int c = 0; c < 4; ++c) {
            int idx = t + c * 256;            // 0..1023 float4 ids
            int row = idx >> 3, kq = idx & 7;
            float4 a = *(const float4*)&X[(size_t)(r0 + row) * 512 + k0 + kq * 4];
            uint2 ph, pl;
            split4((const float*)&a, ph, pl);
            *(uint2*)&Ah[row * 32 + kq * 4] = ph;
            *(uint2*)&Al[row * 32 + kq * 4] = pl;
        }
        // B stage: pre-split Wt rows
#pragma unroll
        for (int c = 0; c < 2; ++c) {
            int idx = t + c * 256;            // 0..511 uint4 ids
            int n = idx >> 2, part = idx & 3;
            size_t src = (size_t)(n0 + n) * 512 + k0 + part * 8;
            *(uint4*)&Bh[n * 32 + part * 8] = *(const uint4*)&Wth[src];
            *(uint4*)&Bl[n * 32 + part * 8] = *(const uint4*)&Wtl[src];
        }
        __syncthreads();

        short8 af[4], alf[4], bf[4], blf[4];
#pragma unroll
        for (int mt = 0; mt < 4; ++mt) {
            af[mt]  = *(const short8*)&Ah[(wm * 64 + mt * 16 + l16) * 32 + quad * 8];
            alf[mt] = *(const short8*)&Al[(wm * 64 + mt * 16 + l16) * 32 + quad * 8];
        }
#pragma unroll
        for (int nt = 0; nt < 4; ++nt) {
            bf[nt]  = *(const short8*)&Bh[(wn * 64 + nt * 16 + l16) * 32 + quad * 8];
            blf[nt] = *(const short8*)&Bl[(wn * 64 + nt * 16 + l16) * 32 + quad * 8];
        }
#pragma unroll
        for (int mt = 0; mt < 4; ++mt)
#pragma unroll
            for (int nt = 0; nt < 4; ++nt) {
                acc[mt][nt] = __builtin_amdgcn_mfma_f32_16x16x32_bf16(af[mt], bf[nt], acc[mt][nt], 0, 0, 0);
                acc[mt][nt] = __builtin_amdgcn_mfma_f32_16x16x32_bf16(af[mt], blf[nt], acc[mt][nt], 0, 0, 0);
                acc[mt][nt] = __builtin_amdgcn_mfma_f32_16x16x32_bf16(alf[mt], bf[nt], acc[mt][nt], 0, 0, 0);
            }
    }

    // Epilogue: wave-uniform mat
    __syncthreads();   // all waves done reading LDS tiles
    const int mat = (n0 + wn * 64) >> 6;
    const int h = mat / 3, j = mat - 3 * h;
    const size_t bh = (size_t)(r0 >> 11) * HEADS + h;
    float* pw = (float*)smem + w * 1088;    // 16 x 68 fp32 per wave
    const float scale = (j == 0) ? 0.125f : 1.0f;

#pragma unroll 1
    for (int mt = 0; mt < 4; ++mt) {
        asm volatile("" ::: "memory");
#pragma unroll
        for (int nt = 0; nt < 4; ++nt)
#pragma unroll
            for (int r = 0; r < 4; ++r)
                pw[(quad * 4 + r) * 68 + nt * 16 + l16] = acc[mt][nt][r] * scale;
        asm volatile("s_waitcnt lgkmcnt(0)" ::: "memory");
        const int sbase = (r0 & 2047) + wm * 64 + mt * 16;
        if (j < 2) {
            unsigned short* dh = (j == 0) ? Qh : Kh;
            unsigned short* dl = (j == 0) ? Ql : Kl;
            float f[16];
            const float* pr = pw + l16 * 68 + quad * 16;
#pragma unroll
            for (int jj = 0; jj < 16; ++jj) f[jj] = pr[jj];
            uint2 h0, l0, h1, l1, h2, l2, h3, l3;
            split4(f, h0, l0); split4(f + 4, h1, l1);
            split4(f + 8, h2, l2); split4(f + 12, h3, l3);
            size_t off = (bh * SEQ + sbase + l16) * 64 + quad * 16;
            *(uint4*)&dh[off]     = make_uint4(h0.x, h0.y, h1.x, h1.y);
            *(uint4*)&dh[off + 8] = make_uint4(h2.x, h2.y, h3.x, h3.y);
            *(uint4*)&dl[off]     = make_uint4(l0.x, l0.y, l1.x, l1.y);
            *(uint4*)&dl[off + 8] = make_uint4(l2.x, l2.y, l3.x, l3.y);
        } else {
            // V: read column d=lane -> transposed rows Vt[d][s]
            float f[16];
#pragma unroll
            for (int ss = 0; ss < 16; ++ss) f[ss] = pw[ss * 68 + lane];
            uint2 h0, l0, h1, l1, h2, l2, h3, l3;
            split4(f, h0, l0); split4(f + 4, h1, l1);
            split4(f + 8, h2, l2); split4(f + 12, h3, l3);
            size_t off = (bh * 64 + lane) * SEQ + sbase;
            *(uint4*)&Vth[off]     = make_uint4(h0.x, h0.y, h1.x, h1.y);
            *(uint4*)&Vth[off + 8] = make_uint4(h2.x, h2.y, h3.x, h3.y);
            *(uint4*)&Vtl[off]     = make_uint4(l0.x, l0.y, l1.x, l1.y);
            *(uint4*)&Vtl[off + 8] = make_uint4(l2.x, l2.y, l3.x, l3.y);
        }
    }
}

// ---------------------------------------------------------------------------
// Kernel 2: flash attention (R4 structure; epilogue emits split-bf16 Oh/Ol).
// ---------------------------------------------------------------------------
__global__ __launch_bounds__(256, 4) void attn_mfma(
        const unsigned short* __restrict__ Qh_g, const unsigned short* __restrict__ Ql_g,
        const unsigned short* __restrict__ Kh_g, const unsigned short* __restrict__ Kl_g,
        const unsigned short* __restrict__ Vth_g, const unsigned short* __restrict__ Vtl_g,
        unsigned short* __restrict__ Oh_g, unsigned short* __restrict__ Ol_g) {
    __shared__ unsigned short Kboth[2][64 * 72];   // P scratch aliases (half-tile)
    __shared__ unsigned short Vsh[64 * 72];
    __shared__ unsigned short Vsl[64 * 72];

    const int t = threadIdx.x;
    const int w = t >> 6, lane = t & 63;
    const int quad = lane >> 4, l16 = lane & 15;
    const int bh = blockIdx.x;
    const int qbase = blockIdx.y * 128 + w * 32;

    unsigned short* Ksh = &Kboth[0][0];
    unsigned short* Ksl = &Kboth[1][0];
    float* pw = (float*)&Kboth[0][0] + w * 1152;

    short8 qhf[2][2], qlf[2][2];
#pragma unroll
    for (int qg = 0; qg < 2; ++qg) {
        const unsigned short* p = Qh_g + ((size_t)bh * SEQ + qbase + qg * 16 + l16) * INNER + quad * 8;
        qhf[qg][0] = *(const short8*)p;
        qhf[qg][1] = *(const short8*)(p + 32);
        const unsigned short* p2 = Ql_g + ((size_t)bh * SEQ + qbase + qg * 16 + l16) * INNER + quad * 8;
        qlf[qg][0] = *(const short8*)p2;
        qlf[qg][1] = *(const short8*)(p2 + 32);
    }

    floatx4 o[2][4];
#pragma unroll
    for (int qg = 0; qg < 2; ++qg)
#pragma unroll
        for (int nt = 0; nt < 4; ++nt) o[qg][nt] = (floatx4)(0.f);
    float mrun[2] = {-1e30f, -1e30f};
    float lrun[2] = {0.f, 0.f};

    const uint4* ksrc_h = (const uint4*)(Kh_g + (size_t)bh * SEQ * INNER);
    const uint4* ksrc_l = (const uint4*)(Kl_g + (size_t)bh * SEQ * INNER);
    const uint4* vsrc_h = (const uint4*)(Vth_g + (size_t)bh * INNER * SEQ);
    const uint4* vsrc_l = (const uint4*)(Vtl_g + (size_t)bh * INNER * SEQ);

    for (int kt = 0; kt < 32; ++kt) {
        __syncthreads();
#pragma unroll
        for (int ii = 0; ii < 2; ++ii) {
            int id = t + ii * 256;
            int row = id >> 3, part = id & 7;
            int dst = row * 72 + part * 8;
            *(uint4*)&Ksh[dst] = ksrc_h[kt * 512 + id];
            *(uint4*)&Ksl[dst] = ksrc_l[kt * 512 + id];
            *(uint4*)&Vsh[dst] = vsrc_h[row * 256 + kt * 8 + part];
            *(uint4*)&Vsl[dst] = vsrc_l[row * 256 + kt * 8 + part];
        }
        __syncthreads();

        floatx4 s[2][4];
#pragma unroll
        for (int st = 0; st < 4; ++st) {
            const unsigned short* ka = &Ksh[(st * 16 + l16) * 72 + quad * 8];
            const unsigned short* kb = &Ksl[(st * 16 + l16) * 72 + quad * 8];
            short8 kh0 = *(const short8*)ka;
            short8 kh1 = *(const short8*)(ka + 32);
            short8 kl0 = *(const short8*)kb;
            short8 kl1 = *(const short8*)(kb + 32);
#pragma unroll
            for (int qg = 0; qg < 2; ++qg) {
                floatx4 a = (floatx4)(0.f);
                a = __builtin_amdgcn_mfma_f32_16x16x32_bf16(kh0, qhf[qg][0], a, 0, 0, 0);
                a = __builtin_amdgcn_mfma_f32_16x16x32_bf16(kh1, qhf[qg][1], a, 0, 0, 0);
                a = __builtin_amdgcn_mfma_f32_16x16x32_bf16(kl0, qhf[qg][0], a, 0, 0, 0);
                a = __builtin_amdgcn_mfma_f32_16x16x32_bf16(kl1, qhf[qg][1], a, 0, 0, 0);
                a = __builtin_amdgcn_mfma_f32_16x16x32_bf16(kh0, qlf[qg][0], a, 0, 0, 0);
                a = __builtin_amdgcn_mfma_f32_16x16x32_bf16(kh1, qlf[qg][1], a, 0, 0, 0);
                s[qg][st] = a;
            }
        }

#pragma unroll
        for (int qg = 0; qg < 2; ++qg) {
            float mloc = s[qg][0][0];
#pragma unroll
            for (int st = 0; st < 4; ++st)
#pragma unroll
                for (int r = 0; r < 4; ++r) mloc = fmaxf(mloc, s[qg][st][r]);
            mloc = fmaxf(mloc, __shfl_xor(mloc, 16));
            mloc = fmaxf(mloc, __shfl_xor(mloc, 32));
            float mn = fmaxf(mrun[qg], mloc);
            float alpha = __expf(mrun[qg] - mn);
            mrun[qg] = mn;
            float rs = 0.f;
#pragma unroll
            for (int st = 0; st < 4; ++st)
#pragma unroll
                for (int r = 0; r < 4; ++r) {
                    float p = __expf(s[qg][st][r] - mn);
                    s[qg][st][r] = p;
                    rs += p;
                }
            rs += __shfl_xor(rs, 16);
            rs += __shfl_xor(rs, 32);
            lrun[qg] = lrun[qg] * alpha + rs;
#pragma unroll
            for (int nt = 0; nt < 4; ++nt) o[qg][nt] = o[qg][nt] * alpha;
        }

        __syncthreads();

#pragma unroll
        for (int half = 0; half < 2; ++half) {
            asm volatile("" ::: "memory");
#pragma unroll
            for (int qg = 0; qg < 2; ++qg)
#pragma unroll
                for (int st2 = 0; st2 < 2; ++st2) {
                    int st = half * 2 + st2;
                    float4 v = make_float4(s[qg][st][0], s[qg][st][1],
                                           s[qg][st][2], s[qg][st][3]);
                    *(float4*)&pw[(qg * 16 + l16) * 36 + st2 * 16 + quad * 4] = v;
                }
            asm volatile("s_waitcnt lgkmcnt(0)" ::: "memory");

            short8 phf[2], plf[2];
#pragma unroll
            for (int qg = 0; qg < 2; ++qg) {
                const float* pr = &pw[(qg * 16 + l16) * 36 + quad * 8];
                float4 pa = *(const float4*)pr;
                float4 pb = *(const float4*)(pr + 4);
                float pv[8] = {pa.x, pa.y, pa.z, pa.w, pb.x, pb.y, pb.z, pb.w};
#pragma unroll
                for (int jj = 0; jj < 8; ++jj) {
                    unsigned short hu, lu;
                    split_bf(pv[jj], hu, lu);
                    phf[qg][jj] = (short)hu;
                    plf[qg][jj] = (short)lu;
                }
            }
#pragma unroll
            for (int nt = 0; nt < 4; ++nt) {
                const unsigned short* va = &Vsh[(nt * 16 + l16) * 72 + half * 32 + quad * 8];
                const unsigned short* vb = &Vsl[(nt * 16 + l16) * 72 + half * 32 + quad * 8];
                short8 vh = *(const short8*)va;
                short8 vl = *(const short8*)vb;
#pragma unroll
                for (int qg = 0; qg < 2; ++qg) {
                    o[qg][nt] = __builtin_amdgcn_mfma_f32_16x16x32_bf16(vh, phf[qg], o[qg][nt], 0, 0, 0);
                    o[qg][nt] = __builtin_amdgcn_mfma_f32_16x16x32_bf16(vh, plf[qg], o[qg][nt], 0, 0, 0);
                    o[qg][nt] = __builtin_amdgcn_mfma_f32_16x16x32_bf16(vl, phf[qg], o[qg][nt], 0, 0, 0);
                }
            }
        }
    }

    // epilogue: split-bf16 O. lane = query qg*16+l16; d = nt*16+quad*4+r
#pragma unroll
    for (int qg = 0; qg < 2; ++qg) {
        float inv = 1.f / lrun[qg];
        size_t row = (size_t)bh * SEQ + qbase + qg * 16 + l16;
#pragma unroll
        for (int nt = 0; nt < 4; ++nt) {
            float f[4] = {o[qg][nt][0] * inv, o[qg][nt][1] * inv,
                          o[qg][nt][2] * inv, o[qg][nt][3] * inv};
            uint2 ph, pl;
            split4(f, ph, pl);
            size_t off = row * 64 + nt * 16 + quad * 4;
            *(uint2*)&Oh_g[off] = ph;
            *(uint2*)&Ol_g[off] = pl;
        }
    }
}

// ---------------------------------------------------------------------------
// Kernel 3: output projection, split-bf16 MFMA.
// Y = concatO(8192x512) @ HK(512x512). A from Oh/Ol (gather over heads).
// ---------------------------------------------------------------------------
__global__ __launch_bounds__(256) void out_proj_mfma(const unsigned short* __restrict__ Oh,
                                                     const unsigned short* __restrict__ Ol,
                                                     const unsigned short* __restrict__ Hth,
                                                     const unsigned short* __restrict__ Htl,
                                                     float* __restrict__ Y) {
    __shared__ __align__(16) unsigned short smem[16384];
    unsigned short* Ah = smem;
    unsigned short* Al = smem + 4096;
    unsigned short* Bh = smem + 8192;
    unsigned short* Bl = smem + 12288;

    const int t = threadIdx.x;
    const int w = t >> 6, lane = t & 63;
    const int quad = lane >> 4, l16 = lane & 15;
    const int wm = w & 1, wn = w >> 1;
    const int r0 = blockIdx.x * 128, n0 = blockIdx.y * 128;
    const int b = r0 >> 11;

    floatx4 acc[4][4];
#pragma unroll
    for (int mt = 0; mt < 4; ++mt)
#pragma unroll
        for (int nt = 0; nt < 4; ++nt) acc[mt][nt] = (floatx4)(0.f);

    for (int ko = 0; ko < 16; ++ko) {
        const int h = ko >> 1, d0 = (ko & 1) * 32;
        const size_t bh = (size_t)b * HEADS + h;
        const int k0 = ko * 32;
        __syncthreads();
#pragma unroll
        for (int c = 0; c < 2; ++c) {
            int idx = t + c * 256;            // 0..511 uint4 ids
            int row = idx >> 2, part = idx & 3;
            size_t src = (bh * SEQ + (r0 & 2047) + row) * 64 + d0 + part * 8;
            *(uint4*)&Ah[row * 32 + part * 8] = *(const uint4*)&Oh[src];
            *(uint4*)&Al[row * 32 + part * 8] = *(const uint4*)&Ol[src];
        }
#pragma unroll
        for (int c = 0; c < 2; ++c) {
            int idx = t + c * 256;
            int n = idx >> 2, part = idx & 3;
            size_t src = (size_t)(n0 + n) * 512 + k0 + part * 8;
            *(uint4*)&Bh[n * 32 + part * 8] = *(const uint4*)&Hth[src];
            *(uint4*)&Bl[n * 32 + part * 8] = *(const uint4*)&Htl[src];
        }
        __syncthreads();

        short8 af[4], alf[4], bf[4], blf[4];
#pragma unroll
        for (int mt = 0; mt < 4; ++mt) {
            af[mt]  = *(const short8*)&Ah[(wm * 64 + mt * 16 + l16) * 32 + quad * 8];
            alf[mt] = *(const short8*)&Al[(wm * 64 + mt * 16 + l16) * 32 + quad * 8];
        }
#pragma unroll
        for (int nt = 0; nt < 4; ++nt) {
            bf[nt]  = *(const short8*)&Bh[(wn * 64 + nt * 16 + l16) * 32 + quad * 8];
            blf[nt] = *(const short8*)&Bl[(wn * 64 + nt * 16 + l16) * 32 + quad * 8];
        }
#pragma unroll
        for (int mt = 0; mt < 4; ++mt)
#pragma unroll
            for (int nt = 0; nt < 4; ++nt) {
                acc[mt][nt] = __builtin_amdgcn_mfma_f32_16x16x32_bf16(af[mt], bf[nt], acc[mt][nt], 0, 0, 0);
                acc[mt][nt] = __builtin_amdgcn_mfma_f32_16x16x32_bf16(af[mt], blf[nt], acc[mt][nt], 0, 0, 0);
                acc[mt][nt] = __builtin_amdgcn_mfma_f32_16x16x32_bf16(alf[mt], bf[nt], acc[mt][nt], 0, 0, 0);
            }
    }

    // direct fp32 stores: quad-rows are 64B contiguous across l16
#pragma unroll
    for (int mt = 0; mt < 4; ++mt)
#pragma unroll
        for (int nt = 0; nt < 4; ++nt)
#pragma unroll
            for (int r = 0; r < 4; ++r)
                Y[(size_t)(r0 + wm * 64 + mt * 16 + quad * 4 + r) * 512 +
                  n0 + wn * 64 + nt * 16 + l16] = acc[mt][nt][r];
}

extern "C" void kernel_launch(void* const* d_in, const int* in_sizes, int n_in,
                              void* d_out, int out_size, void* d_ws, size_t ws_size,
                              hipStream_t stream) {
    const float* x    = (const float*)d_in[0];
    const float* kern = (const float*)d_in[1];
    const float* hk   = (const float*)d_in[2];
    float* y = (float*)d_out;

    unsigned short* Qh  = (unsigned short*)d_ws;
    unsigned short* Ql  = Qh + PER_MAT;
    unsigned short* Kh  = Qh + 2 * PER_MAT;
    unsigned short* Kl  = Qh + 3 * PER_MAT;
    unsigned short* Vth = Qh + 4 * PER_MAT;
    unsigned short* Vtl = Qh + 5 * PER_MAT;
    unsigned short* Oh  = Qh + 6 * PER_MAT;
    unsigned short* Ol  = Qh + 7 * PER_MAT;
    unsigned short* Wth = Qh + 8 * PER_MAT;
    unsigned short* Wtl = Wth + (size_t)1536 * 512;
    unsigned short* Hth = Wtl + (size_t)1536 * 512;
    unsigned short* Htl = Hth + (size_t)512 * 512;

    split_w<<<dim3(24, 8), 256, 0, stream>>>(kern, Wth, Wtl);
    split_hk<<<dim3(8, 8), 256, 0, stream>>>(hk, Hth, Htl);
    qkv_mfma<<<dim3(64, 12), 256, 0, stream>>>(x, Wth, Wtl, Qh, Ql, Kh, Kl, Vth, Vtl);
    attn_mfma<<<dim3(32, 16), 256, 0, stream>>>(Qh, Ql, Kh, Kl, Vth, Vtl, Oh, Ol);
    out_proj_mfma<<<dim3(64, 4), 256, 0, stream>>>(Oh, Ol, Hth, Htl, y);
}

// Round 7
// 409.646 us; speedup vs baseline: 5.8125x; 1.0637x over previous
//
#include <hip/hip_runtime.h>
#include <math.h>

#define D_MODEL 512
#define INNER 64
#define HEADS 8
#define BATCH 4
#define SEQ 2048
#define BHN (BATCH*HEADS)                 // 32
#define PER_MAT ((size_t)BHN*SEQ*INNER)   // 4194304 elements

typedef __attribute__((ext_vector_type(8))) short short8;   // 8 bf16 (4 VGPRs)
typedef __attribute__((ext_vector_type(4))) float floatx4;

// split fp32 -> bf16 hi (truncate) + bf16 lo (truncate of residual)
__device__ __forceinline__ void split_bf(float f, unsigned short& h, unsigned short& l) {
    unsigned int u = __float_as_uint(f);
    h = (unsigned short)(u >> 16);
    float hf = __uint_as_float(u & 0xffff0000u);
    l = (unsigned short)(__float_as_uint(f - hf) >> 16);
}

__device__ __forceinline__ void split4(const float* f, uint2& ph, uint2& pl) {
    unsigned int h[4], l[4];
#pragma unroll
    for (int j = 0; j < 4; ++j) {
        unsigned short hu, lu;
        split_bf(f[j], hu, lu);
        h[j] = hu; l[j] = lu;
    }
    ph.x = h[0] | (h[1] << 16); ph.y = h[2] | (h[3] << 16);
    pl.x = l[0] | (l[1] << 16); pl.y = l[2] | (l[3] << 16);
}

// ---------------------------------------------------------------------------
// Prep 0: X (8192x512 fp32) -> Xh/Xl bf16, same layout. One-shot split so
// qkv_mfma never re-splits (R6: split VALU ran 12x per element).
// ---------------------------------------------------------------------------
__global__ __launch_bounds__(256) void split_x(const float* __restrict__ X,
                                               unsigned short* __restrict__ Xh,
                                               unsigned short* __restrict__ Xl) {
    size_t base = ((size_t)blockIdx.x * 256 + threadIdx.x) * 8;
    float4 a = *(const float4*)&X[base];
    float4 b = *(const float4*)&X[base + 4];
    uint2 h0, l0, h1, l1;
    split4((const float*)&a, h0, l0);
    split4((const float*)&b, h1, l1);
    *(uint4*)&Xh[base] = make_uint4(h0.x, h0.y, h1.x, h1.y);
    *(uint4*)&Xl[base] = make_uint4(l0.x, l0.y, l1.x, l1.y);
}

// ---------------------------------------------------------------------------
// Prep 1: W (24 mats of 512x64 fp32) -> Wt hi/lo bf16 [n=1536][k=512].
// ---------------------------------------------------------------------------
__global__ __launch_bounds__(256) void split_w(const float* __restrict__ kern,
                                               unsigned short* __restrict__ Wth,
                                               unsigned short* __restrict__ Wtl) {
    __shared__ float tile[64 * 65];
    const int t = threadIdx.x;
    const int mat = blockIdx.x, k0 = blockIdx.y * 64;
#pragma unroll
    for (int c = 0; c < 4; ++c) {
        int idx = t + c * 256;
        int kl = idx >> 4, i4 = idx & 15;
        float4 v = *(const float4*)&kern[((size_t)mat * 512 + k0 + kl) * 64 + i4 * 4];
        tile[(i4 * 4 + 0) * 65 + kl] = v.x;
        tile[(i4 * 4 + 1) * 65 + kl] = v.y;
        tile[(i4 * 4 + 2) * 65 + kl] = v.z;
        tile[(i4 * 4 + 3) * 65 + kl] = v.w;
    }
    __syncthreads();
    {
        int i = t >> 2, kq = t & 3;
        uint2 h0, l0, h1, l1, h2, l2, h3, l3;
        float f[16];
#pragma unroll
        for (int jj = 0; jj < 16; ++jj) f[jj] = tile[i * 65 + kq * 16 + jj];
        split4(f, h0, l0); split4(f + 4, h1, l1);
        split4(f + 8, h2, l2); split4(f + 12, h3, l3);
        size_t off = ((size_t)mat * 64 + i) * 512 + k0 + kq * 16;
        *(uint4*)&Wth[off]     = make_uint4(h0.x, h0.y, h1.x, h1.y);
        *(uint4*)&Wth[off + 8] = make_uint4(h2.x, h2.y, h3.x, h3.y);
        *(uint4*)&Wtl[off]     = make_uint4(l0.x, l0.y, l1.x, l1.y);
        *(uint4*)&Wtl[off + 8] = make_uint4(l2.x, l2.y, l3.x, l3.y);
    }
}

// ---------------------------------------------------------------------------
// Prep 2: HK (512x512 fp32) -> HKt hi/lo bf16 [n=512][k=512] (transpose).
// ---------------------------------------------------------------------------
__global__ __launch_bounds__(256) void split_hk(const float* __restrict__ HK,
                                                unsigned short* __restrict__ Hth,
                                                unsigned short* __restrict__ Htl) {
    __shared__ float tile[64 * 65];
    const int t = threadIdx.x;
    const int n0 = blockIdx.x * 64, k0 = blockIdx.y * 64;
#pragma unroll
    for (int c = 0; c < 4; ++c) {
        int idx = t + c * 256;
        int kl = idx >> 4, n4 = idx & 15;
        float4 v = *(const float4*)&HK[(size_t)(k0 + kl) * 512 + n0 + n4 * 4];
        tile[(n4 * 4 + 0) * 65 + kl] = v.x;
        tile[(n4 * 4 + 1) * 65 + kl] = v.y;
        tile[(n4 * 4 + 2) * 65 + kl] = v.z;
        tile[(n4 * 4 + 3) * 65 + kl] = v.w;
    }
    __syncthreads();
    {
        int i = t >> 2, kq = t & 3;
        uint2 h0, l0, h1, l1, h2, l2, h3, l3;
        float f[16];
#pragma unroll
        for (int jj = 0; jj < 16; ++jj) f[jj] = tile[i * 65 + kq * 16 + jj];
        split4(f, h0, l0); split4(f + 4, h1, l1);
        split4(f + 8, h2, l2); split4(f + 12, h3, l3);
        size_t off = (size_t)(n0 + i) * 512 + k0 + kq * 16;
        *(uint4*)&Hth[off]     = make_uint4(h0.x, h0.y, h1.x, h1.y);
        *(uint4*)&Hth[off + 8] = make_uint4(h2.x, h2.y, h3.x, h3.y);
        *(uint4*)&Htl[off]     = make_uint4(l0.x, l0.y, l1.x, l1.y);
        *(uint4*)&Htl[off + 8] = make_uint4(l2.x, l2.y, l3.x, l3.y);
    }
}

// ---------------------------------------------------------------------------
// Kernel 1: QKV projection, split-bf16 MFMA. A-stage now pure uint4 copies
// from pre-split Xh/Xl.
// ---------------------------------------------------------------------------
__global__ __launch_bounds__(256) void qkv_mfma(const unsigned short* __restrict__ Xh,
                                                const unsigned short* __restrict__ Xl,
                                                const unsigned short* __restrict__ Wth,
                                                const unsigned short* __restrict__ Wtl,
                                                unsigned short* __restrict__ Qh,
                                                unsigned short* __restrict__ Ql,
                                                unsigned short* __restrict__ Kh,
                                                unsigned short* __restrict__ Kl,
                                                unsigned short* __restrict__ Vth,
                                                unsigned short* __restrict__ Vtl) {
    __shared__ __align__(16) unsigned short smem[16384];   // 32 KB
    unsigned short* Ah = smem;            // [m][k] 128x32
    unsigned short* Al = smem + 4096;
    unsigned short* Bh = smem + 8192;     // [n][k] 128x32
    unsigned short* Bl = smem + 12288;

    const int t = threadIdx.x;
    const int w = t >> 6, lane = t & 63;
    const int quad = lane >> 4, l16 = lane & 15;
    const int wm = w & 1, wn = w >> 1;
    const int r0 = blockIdx.x * 128, n0 = blockIdx.y * 128;

    floatx4 acc[4][4];
#pragma unroll
    for (int mt = 0; mt < 4; ++mt)
#pragma unroll
        for (int nt = 0; nt < 4; ++nt) acc[mt][nt] = (floatx4)(0.f);

    for (int ko = 0; ko < 16; ++ko) {
        const int k0 = ko * 32;
        __syncthreads();
#pragma unroll
        for (int c = 0; c < 2; ++c) {
            int idx = t + c * 256;            // 0..511: 128 rows x 4 parts
            int row = idx >> 2, part = idx & 3;
            size_t src = (size_t)(r0 + row) * 512 + k0 + part * 8;
            *(uint4*)&Ah[row * 32 + part * 8] = *(const uint4*)&Xh[src];
            *(uint4*)&Al[row * 32 + part * 8] = *(const uint4*)&Xl[src];
        }
#pragma unroll
        for (int c = 0; c < 2; ++c) {
            int idx = t + c * 256;
            int n = idx >> 2, part = idx & 3;
            size_t src = (size_t)(n0 + n) * 512 + k0 + part * 8;
            *(uint4*)&Bh[n * 32 + part * 8] = *(const uint4*)&Wth[src];
            *(uint4*)&Bl[n * 32 + part * 8] = *(const uint4*)&Wtl[src];
        }
        __syncthreads();

        short8 af[4], alf[4], bf[4], blf[4];
#pragma unroll
        for (int mt = 0; mt < 4; ++mt) {
            af[mt]  = *(const short8*)&Ah[(wm * 64 + mt * 16 + l16) * 32 + quad * 8];
            alf[mt] = *(const short8*)&Al[(wm * 64 + mt * 16 + l16) * 32 + quad * 8];
        }
#pragma unroll
        for (int nt = 0; nt < 4; ++nt) {
            bf[nt]  = *(const short8*)&Bh[(wn * 64 + nt * 16 + l16) * 32 + quad * 8];
            blf[nt] = *(const short8*)&Bl[(wn * 64 + nt * 16 + l16) * 32 + quad * 8];
        }
#pragma unroll
        for (int mt = 0; mt < 4; ++mt)
#pragma unroll
            for (int nt = 0; nt < 4; ++nt) {
                acc[mt][nt] = __builtin_amdgcn_mfma_f32_16x16x32_bf16(af[mt], bf[nt], acc[mt][nt], 0, 0, 0);
                acc[mt][nt] = __builtin_amdgcn_mfma_f32_16x16x32_bf16(af[mt], blf[nt], acc[mt][nt], 0, 0, 0);
                acc[mt][nt] = __builtin_amdgcn_mfma_f32_16x16x32_bf16(alf[mt], bf[nt], acc[mt][nt], 0, 0, 0);
            }
    }

    // Epilogue (R6-verified): wave-uniform mat, LDS repack, coalesced stores
    __syncthreads();
    const int mat = (n0 + wn * 64) >> 6;
    const int h = mat / 3, j = mat - 3 * h;
    const size_t bh = (size_t)(r0 >> 11) * HEADS + h;
    float* pw = (float*)smem + w * 1088;    // 16 x 68 fp32 per wave
    const float scale = (j == 0) ? 0.125f : 1.0f;

#pragma unroll 1
    for (int mt = 0; mt < 4; ++mt) {
        asm volatile("" ::: "memory");
#pragma unroll
        for (int nt = 0; nt < 4; ++nt)
#pragma unroll
            for (int r = 0; r < 4; ++r)
                pw[(quad * 4 + r) * 68 + nt * 16 + l16] = acc[mt][nt][r] * scale;
        asm volatile("s_waitcnt lgkmcnt(0)" ::: "memory");
        const int sbase = (r0 & 2047) + wm * 64 + mt * 16;
        if (j < 2) {
            unsigned short* dh = (j == 0) ? Qh : Kh;
            unsigned short* dl = (j == 0) ? Ql : Kl;
            float f[16];
            const float* pr = pw + l16 * 68 + quad * 16;
#pragma unroll
            for (int jj = 0; jj < 16; ++jj) f[jj] = pr[jj];
            uint2 h0, l0, h1, l1, h2, l2, h3, l3;
            split4(f, h0, l0); split4(f + 4, h1, l1);
            split4(f + 8, h2, l2); split4(f + 12, h3, l3);
            size_t off = (bh * SEQ + sbase + l16) * 64 + quad * 16;
            *(uint4*)&dh[off]     = make_uint4(h0.x, h0.y, h1.x, h1.y);
            *(uint4*)&dh[off + 8] = make_uint4(h2.x, h2.y, h3.x, h3.y);
            *(uint4*)&dl[off]     = make_uint4(l0.x, l0.y, l1.x, l1.y);
            *(uint4*)&dl[off + 8] = make_uint4(l2.x, l2.y, l3.x, l3.y);
        } else {
            float f[16];
#pragma unroll
            for (int ss = 0; ss < 16; ++ss) f[ss] = pw[ss * 68 + lane];
            uint2 h0, l0, h1, l1, h2, l2, h3, l3;
            split4(f, h0, l0); split4(f + 4, h1, l1);
            split4(f + 8, h2, l2); split4(f + 12, h3, l3);
            size_t off = (bh * 64 + lane) * SEQ + sbase;
            *(uint4*)&Vth[off]     = make_uint4(h0.x, h0.y, h1.x, h1.y);
            *(uint4*)&Vth[off + 8] = make_uint4(h2.x, h2.y, h3.x, h3.y);
            *(uint4*)&Vtl[off]     = make_uint4(l0.x, l0.y, l1.x, l1.y);
            *(uint4*)&Vtl[off + 8] = make_uint4(l2.x, l2.y, l3.x, l3.y);
        }
    }
}

// ---------------------------------------------------------------------------
// Kernel 2: flash attention. R7 changes: dedicated P scratch (no aliasing,
// no barrier C -> 2 barriers/tile) + register prefetch of next K/V tile
// (global loads fly across the whole compute phase).
// LDS = 36864 (K/V) + 18432 (P) = 55.3 KB; grid 512 = 2 blocks/CU.
// ---------------------------------------------------------------------------
__global__ __launch_bounds__(256) void attn_mfma(
        const unsigned short* __restrict__ Qh_g, const unsigned short* __restrict__ Ql_g,
        const unsigned short* __restrict__ Kh_g, const unsigned short* __restrict__ Kl_g,
        const unsigned short* __restrict__ Vth_g, const unsigned short* __restrict__ Vtl_g,
        unsigned short* __restrict__ Oh_g, unsigned short* __restrict__ Ol_g) {
    __shared__ unsigned short Ksh[64 * 72];
    __shared__ unsigned short Ksl[64 * 72];
    __shared__ unsigned short Vsh[64 * 72];        // [dim][key]
    __shared__ unsigned short Vsl[64 * 72];
    __shared__ float Pw[4][32 * 36];               // per-wave P scratch (dedicated)

    const int t = threadIdx.x;
    const int w = t >> 6, lane = t & 63;
    const int quad = lane >> 4, l16 = lane & 15;
    const int bh = blockIdx.x;
    const int qbase = blockIdx.y * 128 + w * 32;
    float* pw = &Pw[w][0];

    short8 qhf[2][2], qlf[2][2];
#pragma unroll
    for (int qg = 0; qg < 2; ++qg) {
        const unsigned short* p = Qh_g + ((size_t)bh * SEQ + qbase + qg * 16 + l16) * INNER + quad * 8;
        qhf[qg][0] = *(const short8*)p;
        qhf[qg][1] = *(const short8*)(p + 32);
        const unsigned short* p2 = Ql_g + ((size_t)bh * SEQ + qbase + qg * 16 + l16) * INNER + quad * 8;
        qlf[qg][0] = *(const short8*)p2;
        qlf[qg][1] = *(const short8*)(p2 + 32);
    }

    floatx4 o[2][4];
#pragma unroll
    for (int qg = 0; qg < 2; ++qg)
#pragma unroll
        for (int nt = 0; nt < 4; ++nt) o[qg][nt] = (floatx4)(0.f);
    float mrun[2] = {-1e30f, -1e30f};
    float lrun[2] = {0.f, 0.f};

    const uint4* ksrc_h = (const uint4*)(Kh_g + (size_t)bh * SEQ * INNER);
    const uint4* ksrc_l = (const uint4*)(Kl_g + (size_t)bh * SEQ * INNER);
    const uint4* vsrc_h = (const uint4*)(Vth_g + (size_t)bh * INNER * SEQ);
    const uint4* vsrc_l = (const uint4*)(Vtl_g + (size_t)bh * INNER * SEQ);

    // prefetch tile 0 into registers
    uint4 pkh[2], pkl[2], pvh[2], pvl[2];
#pragma unroll
    for (int ii = 0; ii < 2; ++ii) {
        int id = t + ii * 256, row = id >> 3, part = id & 7;
        pkh[ii] = ksrc_h[id];
        pkl[ii] = ksrc_l[id];
        pvh[ii] = vsrc_h[row * 256 + part];
        pvl[ii] = vsrc_l[row * 256 + part];
    }

    for (int kt = 0; kt < 32; ++kt) {
        __syncthreads();   // (A) prior tile's readers done; drains prefetch
#pragma unroll
        for (int ii = 0; ii < 2; ++ii) {
            int id = t + ii * 256, row = id >> 3, part = id & 7;
            int dst = row * 72 + part * 8;
            *(uint4*)&Ksh[dst] = pkh[ii];
            *(uint4*)&Ksl[dst] = pkl[ii];
            *(uint4*)&Vsh[dst] = pvh[ii];
            *(uint4*)&Vsl[dst] = pvl[ii];
        }
        if (kt + 1 < 32) {   // issue next tile's loads; consumed next iter
#pragma unroll
            for (int ii = 0; ii < 2; ++ii) {
                int id = t + ii * 256, row = id >> 3, part = id & 7;
                pkh[ii] = ksrc_h[(kt + 1) * 512 + id];
                pkl[ii] = ksrc_l[(kt + 1) * 512 + id];
                pvh[ii] = vsrc_h[row * 256 + (kt + 1) * 8 + part];
                pvl[ii] = vsrc_l[row * 256 + (kt + 1) * 8 + part];
            }
        }
        __syncthreads();   // (B) staging visible

        // ---- S^T: 4 subtiles of 16 keys ----
        floatx4 s[2][4];
#pragma unroll
        for (int st = 0; st < 4; ++st) {
            const unsigned short* ka = &Ksh[(st * 16 + l16) * 72 + quad * 8];
            const unsigned short* kb = &Ksl[(st * 16 + l16) * 72 + quad * 8];
            short8 kh0 = *(const short8*)ka;
            short8 kh1 = *(const short8*)(ka + 32);
            short8 kl0 = *(const short8*)kb;
            short8 kl1 = *(const short8*)(kb + 32);
#pragma unroll
            for (int qg = 0; qg < 2; ++qg) {
                floatx4 a = (floatx4)(0.f);
                a = __builtin_amdgcn_mfma_f32_16x16x32_bf16(kh0, qhf[qg][0], a, 0, 0, 0);
                a = __builtin_amdgcn_mfma_f32_16x16x32_bf16(kh1, qhf[qg][1], a, 0, 0, 0);
                a = __builtin_amdgcn_mfma_f32_16x16x32_bf16(kl0, qhf[qg][0], a, 0, 0, 0);
                a = __builtin_amdgcn_mfma_f32_16x16x32_bf16(kl1, qhf[qg][1], a, 0, 0, 0);
                a = __builtin_amdgcn_mfma_f32_16x16x32_bf16(kh0, qlf[qg][0], a, 0, 0, 0);
                a = __builtin_amdgcn_mfma_f32_16x16x32_bf16(kh1, qlf[qg][1], a, 0, 0, 0);
                s[qg][st] = a;
            }
        }

        // ---- online softmax ----
#pragma unroll
        for (int qg = 0; qg < 2; ++qg) {
            float mloc = s[qg][0][0];
#pragma unroll
            for (int st = 0; st < 4; ++st)
#pragma unroll
                for (int r = 0; r < 4; ++r) mloc = fmaxf(mloc, s[qg][st][r]);
            mloc = fmaxf(mloc, __shfl_xor(mloc, 16));
            mloc = fmaxf(mloc, __shfl_xor(mloc, 32));
            float mn = fmaxf(mrun[qg], mloc);
            float alpha = __expf(mrun[qg] - mn);
            mrun[qg] = mn;
            float rs = 0.f;
#pragma unroll
            for (int st = 0; st < 4; ++st)
#pragma unroll
                for (int r = 0; r < 4; ++r) {
                    float p = __expf(s[qg][st][r] - mn);
                    s[qg][st][r] = p;
                    rs += p;
                }
            rs += __shfl_xor(rs, 16);
            rs += __shfl_xor(rs, 32);
            lrun[qg] = lrun[qg] * alpha + rs;
#pragma unroll
            for (int nt = 0; nt < 4; ++nt) o[qg][nt] = o[qg][nt] * alpha;
        }

        // ---- PV in two halves; P transpose via dedicated per-wave LDS ----
#pragma unroll
        for (int half = 0; half < 2; ++half) {
            asm volatile("" ::: "memory");
#pragma unroll
            for (int qg = 0; qg < 2; ++qg)
#pragma unroll
                for (int st2 = 0; st2 < 2; ++st2) {
                    int st = half * 2 + st2;
                    float4 v = make_float4(s[qg][st][0], s[qg][st][1],
                                           s[qg][st][2], s[qg][st][3]);
                    *(float4*)&pw[(qg * 16 + l16) * 36 + st2 * 16 + quad * 4] = v;
                }
            asm volatile("s_waitcnt lgkmcnt(0)" ::: "memory");

            short8 phf[2], plf[2];
#pragma unroll
            for (int qg = 0; qg < 2; ++qg) {
                const float* pr = &pw[(qg * 16 + l16) * 36 + quad * 8];
                float4 pa = *(const float4*)pr;
                float4 pb = *(const float4*)(pr + 4);
                float pv[8] = {pa.x, pa.y, pa.z, pa.w, pb.x, pb.y, pb.z, pb.w};
#pragma unroll
                for (int jj = 0; jj < 8; ++jj) {
                    unsigned short hu, lu;
                    split_bf(pv[jj], hu, lu);
                    phf[qg][jj] = (short)hu;
                    plf[qg][jj] = (short)lu;
                }
            }
#pragma unroll
            for (int nt = 0; nt < 4; ++nt) {
                const unsigned short* va = &Vsh[(nt * 16 + l16) * 72 + half * 32 + quad * 8];
                const unsigned short* vb = &Vsl[(nt * 16 + l16) * 72 + half * 32 + quad * 8];
                short8 vh = *(const short8*)va;
                short8 vl = *(const short8*)vb;
#pragma unroll
                for (int qg = 0; qg < 2; ++qg) {
                    o[qg][nt] = __builtin_amdgcn_mfma_f32_16x16x32_bf16(vh, phf[qg], o[qg][nt], 0, 0, 0);
                    o[qg][nt] = __builtin_amdgcn_mfma_f32_16x16x32_bf16(vh, plf[qg], o[qg][nt], 0, 0, 0);
                    o[qg][nt] = __builtin_amdgcn_mfma_f32_16x16x32_bf16(vl, phf[qg], o[qg][nt], 0, 0, 0);
                }
            }
        }
    }

    // epilogue: split-bf16 O
#pragma unroll
    for (int qg = 0; qg < 2; ++qg) {
        float inv = 1.f / lrun[qg];
        size_t row = (size_t)bh * SEQ + qbase + qg * 16 + l16;
#pragma unroll
        for (int nt = 0; nt < 4; ++nt) {
            float f[4] = {o[qg][nt][0] * inv, o[qg][nt][1] * inv,
                          o[qg][nt][2] * inv, o[qg][nt][3] * inv};
            uint2 ph, pl;
            split4(f, ph, pl);
            size_t off = row * 64 + nt * 16 + quad * 4;
            *(uint2*)&Oh_g[off] = ph;
            *(uint2*)&Ol_g[off] = pl;
        }
    }
}

// ---------------------------------------------------------------------------
// Kernel 3: output projection, split-bf16 MFMA. R7: 64x128 tiles, grid
// (128,4) = 512 blocks = 2 blocks/CU (was 1). Wave = 32 rows x 64 cols.
// ---------------------------------------------------------------------------
__global__ __launch_bounds__(256) void out_proj_mfma(const unsigned short* __restrict__ Oh,
                                                     const unsigned short* __restrict__ Ol,
                                                     const unsigned short* __restrict__ Hth,
                                                     const unsigned short* __restrict__ Htl,
                                                     float* __restrict__ Y) {
    __shared__ __align__(16) unsigned short smem[12288];   // 24.6 KB
    unsigned short* Ah = smem;            // 64 x 32
    unsigned short* Al = smem + 2048;
    unsigned short* Bh = smem + 4096;     // 128 x 32
    unsigned short* Bl = smem + 8192;

    const int t = threadIdx.x;
    const int w = t >> 6, lane = t & 63;
    const int quad = lane >> 4, l16 = lane & 15;
    const int wm = w & 1, wn = w >> 1;
    const int r0 = blockIdx.x * 64, n0 = blockIdx.y * 128;
    const int b = r0 >> 11;

    floatx4 acc[2][4];
#pragma unroll
    for (int mt = 0; mt < 2; ++mt)
#pragma unroll
        for (int nt = 0; nt < 4; ++nt) acc[mt][nt] = (floatx4)(0.f);

    for (int ko = 0; ko < 16; ++ko) {
        const int h = ko >> 1, d0 = (ko & 1) * 32;
        const size_t bh = (size_t)b * HEADS + h;
        const int k0 = ko * 32;
        __syncthreads();
        {
            int row = t >> 2, part = t & 3;   // 64 rows x 4 parts = 256
            size_t src = (bh * SEQ + (r0 & 2047) + row) * 64 + d0 + part * 8;
            *(uint4*)&Ah[row * 32 + part * 8] = *(const uint4*)&Oh[src];
            *(uint4*)&Al[row * 32 + part * 8] = *(const uint4*)&Ol[src];
        }
#pragma unroll
        for (int c = 0; c < 2; ++c) {
            int idx = t + c * 256;            // 128 cols x 4 parts = 512
            int n = idx >> 2, part = idx & 3;
            size_t src = (size_t)(n0 + n) * 512 + k0 + part * 8;
            *(uint4*)&Bh[n * 32 + part * 8] = *(const uint4*)&Hth[src];
            *(uint4*)&Bl[n * 32 + part * 8] = *(const uint4*)&Htl[src];
        }
        __syncthreads();

        short8 af[2], alf[2], bf[4], blf[4];
#pragma unroll
        for (int mt = 0; mt < 2; ++mt) {
            af[mt]  = *(const short8*)&Ah[(wm * 32 + mt * 16 + l16) * 32 + quad * 8];
            alf[mt] = *(const short8*)&Al[(wm * 32 + mt * 16 + l16) * 32 + quad * 8];
        }
#pragma unroll
        for (int nt = 0; nt < 4; ++nt) {
            bf[nt]  = *(const short8*)&Bh[(wn * 64 + nt * 16 + l16) * 32 + quad * 8];
            blf[nt] = *(const short8*)&Bl[(wn * 64 + nt * 16 + l16) * 32 + quad * 8];
        }
#pragma unroll
        for (int mt = 0; mt < 2; ++mt)
#pragma unroll
            for (int nt = 0; nt < 4; ++nt) {
                acc[mt][nt] = __builtin_amdgcn_mfma_f32_16x16x32_bf16(af[mt], bf[nt], acc[mt][nt], 0, 0, 0);
                acc[mt][nt] = __builtin_amdgcn_mfma_f32_16x16x32_bf16(af[mt], blf[nt], acc[mt][nt], 0, 0, 0);
                acc[mt][nt] = __builtin_amdgcn_mfma_f32_16x16x32_bf16(alf[mt], bf[nt], acc[mt][nt], 0, 0, 0);
            }
    }

#pragma unroll
    for (int mt = 0; mt < 2; ++mt)
#pragma unroll
        for (int nt = 0; nt < 4; ++nt)
#pragma unroll
            for (int r = 0; r < 4; ++r)
                Y[(size_t)(r0 + wm * 32 + mt * 16 + quad * 4 + r) * 512 +
                  n0 + wn * 64 + nt * 16 + l16] = acc[mt][nt][r];
}

extern "C" void kernel_launch(void* const* d_in, const int* in_sizes, int n_in,
                              void* d_out, int out_size, void* d_ws, size_t ws_size,
                              hipStream_t stream) {
    const float* x    = (const float*)d_in[0];
    const float* kern = (const float*)d_in[1];
    const float* hk   = (const float*)d_in[2];
    float* y = (float*)d_out;

    unsigned short* Qh  = (unsigned short*)d_ws;
    unsigned short* Ql  = Qh + PER_MAT;
    unsigned short* Kh  = Qh + 2 * PER_MAT;
    unsigned short* Kl  = Qh + 3 * PER_MAT;
    unsigned short* Vth = Qh + 4 * PER_MAT;
    unsigned short* Vtl = Qh + 5 * PER_MAT;
    // Xh/Xl alias Oh/Ol: X is dead by the time attn writes O (stream order)
    unsigned short* Oh  = Qh + 6 * PER_MAT;
    unsigned short* Ol  = Qh + 7 * PER_MAT;
    unsigned short* Xh  = Oh;
    unsigned short* Xl  = Ol;
    unsigned short* Wth = Qh + 8 * PER_MAT;
    unsigned short* Wtl = Wth + (size_t)1536 * 512;
    unsigned short* Hth = Wtl + (size_t)1536 * 512;
    unsigned short* Htl = Hth + (size_t)512 * 512;

    split_x<<<dim3(2048), 256, 0, stream>>>(x, Xh, Xl);
    split_w<<<dim3(24, 8), 256, 0, stream>>>(kern, Wth, Wtl);
    split_hk<<<dim3(8, 8), 256, 0, stream>>>(hk, Hth, Htl);
    qkv_mfma<<<dim3(64, 12), 256, 0, stream>>>(Xh, Xl, Wth, Wtl, Qh, Ql, Kh, Kl, Vth, Vtl);
    attn_mfma<<<dim3(32, 16), 256, 0, stream>>>(Qh, Ql, Kh, Kl, Vth, Vtl, Oh, Ol);
    out_proj_mfma<<<dim3(128, 4), 256, 0, stream>>>(Oh, Ol, Hth, Htl, y);
}